// Round 2
// baseline (6351.096 us; speedup 1.0000x reference)
//
#include <hip/hip_runtime.h>
#include <hip/hip_bf16.h>

namespace {

constexpr int T = 8, HS = 14, WSP = 14, HW = 196;
constexpr int C = 768, NH = 8, HD = 96;
constexpr int NTOK = 1568;
constexpr int BHT = 1024;          // B*NH*T
constexpr int DW2 = 49;            // 7*7 displacement window
constexpr int C3 = 2304;           // 3*C
constexpr int CHW = HD * HW;       // 18816
constexpr int NROWS = 25088;       // B*NTOK

using bf16 = __hip_bfloat16;

__device__ __forceinline__ float b2f(bf16 h) { return __bfloat162float(h); }
__device__ __forceinline__ bf16 f2b(float f) { return __float2bfloat16(f); }

// ---------------------------------------------------------------------------
// K1: QKV GEMM (25088 x 768) @ (768 x 2304), scatter to bf16 Q / K(shifted) / V.
// Q layout: [bt][c][hw]  (bt = (b*8+head)*8+t), K same (temporal shift applied
// on write: value k[t] lands in slot t-1, and t==7 also lands in slot 7).
// V layout: [bt][hw][c].
// ---------------------------------------------------------------------------
__global__ __launch_bounds__(256) void gemm_qkv_scatter(
    const float* __restrict__ A, const float* __restrict__ W,
    bf16* __restrict__ Qo, bf16* __restrict__ Ko, bf16* __restrict__ Vo) {
  __shared__ __align__(16) float As[16][64];
  __shared__ __align__(16) float Bs[16][64];
  const int ct = blockIdx.x * 64;
  const int rt = blockIdx.y * 64;
  const int tid = threadIdx.x;
  const int l = tid * 4;
  const int lm = l >> 4, lk = l & 15;   // A-tile load coords (64 x 16)
  const int bk = l >> 6, bn = l & 63;   // B-tile load coords (16 x 64)
  const int ty4 = (tid >> 4) * 4, tx4 = (tid & 15) * 4;
  float acc[4][4] = {};
  for (int k0 = 0; k0 < C; k0 += 16) {
    const float4 a4 = *(const float4*)(A + (size_t)(rt + lm) * C + k0 + lk);
    const float4 b4 = *(const float4*)(W + (size_t)(k0 + bk) * C3 + ct + bn);
    __syncthreads();
    As[lk + 0][lm] = a4.x; As[lk + 1][lm] = a4.y;
    As[lk + 2][lm] = a4.z; As[lk + 3][lm] = a4.w;
    *(float4*)&Bs[bk][bn] = b4;
    __syncthreads();
#pragma unroll
    for (int kk = 0; kk < 16; ++kk) {
      const float4 av = *(const float4*)&As[kk][ty4];
      const float4 bv = *(const float4*)&Bs[kk][tx4];
      const float a0[4] = {av.x, av.y, av.z, av.w};
      const float b0[4] = {bv.x, bv.y, bv.z, bv.w};
#pragma unroll
      for (int i = 0; i < 4; ++i)
#pragma unroll
        for (int j = 0; j < 4; ++j) acc[i][j] += a0[i] * b0[j];
    }
  }
#pragma unroll
  for (int i = 0; i < 4; ++i) {
    const int row = rt + ty4 + i;
    const int b_ = row / NTOK, n = row % NTOK;
    const int t = n / HW, hw = n % HW;
#pragma unroll
    for (int j = 0; j < 4; ++j) {
      const int col = ct + tx4 + j;
      const bf16 v = f2b(acc[i][j]);
      const int s = col / C, rem = col % C;
      const int head = rem / HD, ch = rem % HD;
      const int bh = b_ * NH + head;
      if (s == 0) {
        Qo[((size_t)(bh * T + t) * HD + ch) * HW + hw] = v;
      } else if (s == 1) {
        if (t >= 1) Ko[((size_t)(bh * T + (t - 1)) * HD + ch) * HW + hw] = v;
        if (t == T - 1) Ko[((size_t)(bh * T + t) * HD + ch) * HW + hw] = v;
      } else {
        Vo[((size_t)(bh * T + t) * HW + hw) * HD + ch] = v;
      }
    }
  }
}

// ---------------------------------------------------------------------------
// K2: in-place l2norm over channel dim for X[bt][c][hw] (per bt, per hw).
// fp32 accumulation over bf16 values.
// ---------------------------------------------------------------------------
__global__ __launch_bounds__(256) void l2norm_ip(bf16* __restrict__ X) {
  const int bt = blockIdx.x;
  const int hw = threadIdx.x;
  if (hw >= HW) return;
  bf16* p = X + (size_t)bt * CHW + hw;
  float s = 0.f;
#pragma unroll
  for (int c = 0; c < HD; ++c) { const float v = b2f(p[c * HW]); s += v * v; }
  const float inv = 1.f / fmaxf(sqrtf(s), 1e-12f);
#pragma unroll
  for (int c = 0; c < HD; ++c) p[c * HW] = f2b(b2f(p[c * HW]) * inv);
}

// ---------------------------------------------------------------------------
// K3: cost volume. corr[bt][p][hw] = <q[:,hw], k[:,hw+disp(p)]> (0 if OOB)
//                                   + pos_embed[p][hw]
// ---------------------------------------------------------------------------
__global__ __launch_bounds__(256) void corr_kernel(
    const bf16* __restrict__ Q, const bf16* __restrict__ K,
    const float* __restrict__ pos, float* __restrict__ corr) {
  __shared__ __align__(16) bf16 qb[CHW];
  __shared__ __align__(16) bf16 kb[CHW];
  const int bt = blockIdx.x;
  const int tid = threadIdx.x;
  {
    const uint4* qs = (const uint4*)(Q + (size_t)bt * CHW);
    const uint4* ks = (const uint4*)(K + (size_t)bt * CHW);
    uint4* qd = (uint4*)qb;
    uint4* kd = (uint4*)kb;
    for (int i = tid; i < CHW / 8; i += 256) { qd[i] = qs[i]; kd[i] = ks[i]; }
  }
  __syncthreads();
  for (int idx = tid; idx < DW2 * HW; idx += 256) {
    const int p = idx / HW, hw = idx % HW;
    const int h = hw / WSP, w = hw % WSP;
    const int h2 = h + p / 7 - 3, w2 = w + p % 7 - 3;
    float acc = 0.f;
    if ((unsigned)h2 < (unsigned)HS && (unsigned)w2 < (unsigned)WSP) {
      const int hw2 = h2 * WSP + w2;
#pragma unroll 8
      for (int c = 0; c < HD; ++c)
        acc += b2f(qb[c * HW + hw]) * b2f(kb[c * HW + hw2]);
    }
    corr[((size_t)bt * DW2 + p) * HW + hw] = acc + pos[idx];
  }
}

// ---------------------------------------------------------------------------
// K4: appearance branch, fused per (bt, 49-row tile):
//     S = q^T k  -> softmax rows -> 0.5 * P @ V  -> merged (=)
// merged layout: (B, NTOK, C) row-major, bf16.
// ---------------------------------------------------------------------------
__global__ __launch_bounds__(256) void app_kernel(
    const bf16* __restrict__ Q, const bf16* __restrict__ K,
    const bf16* __restrict__ V, bf16* __restrict__ merged) {
  __shared__ __align__(16) bf16 kb[CHW];       // 37.6 KB
  __shared__ __align__(16) bf16 vb[HW * HD];   // 37.6 KB
  __shared__ __align__(16) bf16 qt[HD * 49];   //  9.4 KB
  __shared__ __align__(16) float srow[49 * HW];// 38.4 KB
  const int bt = blockIdx.x;
  const int r0 = blockIdx.y * 49;
  const int tid = threadIdx.x;
  {
    const uint4* ks = (const uint4*)(K + (size_t)bt * CHW);
    const uint4* vs = (const uint4*)(V + (size_t)bt * CHW);
    uint4* kd = (uint4*)kb;
    uint4* vd = (uint4*)vb;
    for (int i = tid; i < CHW / 8; i += 256) { kd[i] = ks[i]; vd[i] = vs[i]; }
  }
  for (int i = tid; i < HD * 49; i += 256) {
    const int c = i / 49, n = i % 49;
    qt[i] = Q[(size_t)bt * CHW + c * HW + r0 + n];
  }
  __syncthreads();
  // scores
  for (int idx = tid; idx < 49 * HW; idx += 256) {
    const int n = idx / HW, m = idx % HW;
    float acc = 0.f;
#pragma unroll 8
    for (int c = 0; c < HD; ++c)
      acc += b2f(qt[c * 49 + n]) * b2f(kb[c * HW + m]);
    srow[idx] = acc;
  }
  __syncthreads();
  // row softmax (x0.5), one wave per row
  const int wid = tid >> 6, lane = tid & 63;
  for (int n = wid; n < 49; n += 4) {
    float* r = srow + n * HW;
    const float x0 = r[lane], x1 = r[lane + 64], x2 = r[lane + 128];
    const float x3 = (lane < HW - 192) ? r[lane + 192] : -1e30f;
    float mx = fmaxf(fmaxf(x0, x1), fmaxf(x2, x3));
#pragma unroll
    for (int off = 32; off > 0; off >>= 1) mx = fmaxf(mx, __shfl_xor(mx, off));
    const float e0 = __expf(x0 - mx), e1 = __expf(x1 - mx), e2 = __expf(x2 - mx);
    const float e3 = (lane < HW - 192) ? __expf(x3 - mx) : 0.f;
    float sum = e0 + e1 + e2 + e3;
#pragma unroll
    for (int off = 32; off > 0; off >>= 1) sum += __shfl_xor(sum, off);
    const float sc = 0.5f / sum;
    r[lane] = e0 * sc; r[lane + 64] = e1 * sc; r[lane + 128] = e2 * sc;
    if (lane < HW - 192) r[lane + 192] = e3 * sc;
  }
  __syncthreads();
  // P @ V, write (=)
  const int b_ = bt >> 6, head = (bt >> 3) & 7, t = bt & 7;
  for (int idx = tid; idx < 49 * HD; idx += 256) {
    const int n = idx / HD, c = idx % HD;
    float acc = 0.f;
#pragma unroll 4
    for (int m = 0; m < HW; ++m)
      acc += srow[n * HW + m] * b2f(vb[m * HD + c]);
    merged[((size_t)b_ * NTOK + t * HW + r0 + n) * C + head * HD + c] = f2b(acc);
  }
}

// ---------------------------------------------------------------------------
// K5: motion branch, fused per (bt, 49-row tile):
//     M = corr^T corr -> softmax rows -> 0.5 * P @ V -> merged (+=)
// ---------------------------------------------------------------------------
__global__ __launch_bounds__(256) void motion_kernel(
    const float* __restrict__ corr, const bf16* __restrict__ V,
    bf16* __restrict__ merged) {
  __shared__ __align__(16) float cb[DW2 * HW];  // 38.4 KB
  __shared__ __align__(16) bf16 vb[HW * HD];    // 37.6 KB
  __shared__ __align__(16) float mrow[49 * HW]; // 38.4 KB
  const int bt = blockIdx.x;
  const int r0 = blockIdx.y * 49;
  const int tid = threadIdx.x;
  {
    const uint4* cs = (const uint4*)(corr + (size_t)bt * DW2 * HW);
    uint4* cd = (uint4*)cb;
    for (int i = tid; i < DW2 * HW / 4; i += 256) cd[i] = cs[i];
    const uint4* vs = (const uint4*)(V + (size_t)bt * CHW);
    uint4* vd = (uint4*)vb;
    for (int i = tid; i < CHW / 8; i += 256) vd[i] = vs[i];
  }
  __syncthreads();
  for (int idx = tid; idx < 49 * HW; idx += 256) {
    const int n = idx / HW, m = idx % HW;
    float acc = 0.f;
#pragma unroll
    for (int u = 0; u < DW2; ++u) acc += cb[u * HW + r0 + n] * cb[u * HW + m];
    mrow[idx] = acc;
  }
  __syncthreads();
  const int wid = tid >> 6, lane = tid & 63;
  for (int n = wid; n < 49; n += 4) {
    float* r = mrow + n * HW;
    const float x0 = r[lane], x1 = r[lane + 64], x2 = r[lane + 128];
    const float x3 = (lane < HW - 192) ? r[lane + 192] : -1e30f;
    float mx = fmaxf(fmaxf(x0, x1), fmaxf(x2, x3));
#pragma unroll
    for (int off = 32; off > 0; off >>= 1) mx = fmaxf(mx, __shfl_xor(mx, off));
    const float e0 = __expf(x0 - mx), e1 = __expf(x1 - mx), e2 = __expf(x2 - mx);
    const float e3 = (lane < HW - 192) ? __expf(x3 - mx) : 0.f;
    float sum = e0 + e1 + e2 + e3;
#pragma unroll
    for (int off = 32; off > 0; off >>= 1) sum += __shfl_xor(sum, off);
    const float sc = 0.5f / sum;
    r[lane] = e0 * sc; r[lane + 64] = e1 * sc; r[lane + 128] = e2 * sc;
    if (lane < HW - 192) r[lane + 192] = e3 * sc;
  }
  __syncthreads();
  const int b_ = bt >> 6, head = (bt >> 3) & 7, t = bt & 7;
  for (int idx = tid; idx < 49 * HD; idx += 256) {
    const int n = idx / HD, c = idx % HD;
    float acc = 0.f;
#pragma unroll 4
    for (int m = 0; m < HW; ++m)
      acc += mrow[n * HW + m] * b2f(vb[m * HD + c]);
    const size_t o = ((size_t)b_ * NTOK + t * HW + r0 + n) * C + head * HD + c;
    merged[o] = f2b(b2f(merged[o]) + acc);
  }
}

// ---------------------------------------------------------------------------
// K6: proj GEMM (25088 x 768) bf16 @ (768 x 768) f32 + bias -> out f32
// ---------------------------------------------------------------------------
__global__ __launch_bounds__(256) void gemm_proj(
    const bf16* __restrict__ A, const float* __restrict__ W,
    const float* __restrict__ bias, float* __restrict__ out) {
  __shared__ __align__(16) float As[16][64];
  __shared__ __align__(16) float Bs[16][64];
  const int ct = blockIdx.x * 64;
  const int rt = blockIdx.y * 64;
  const int tid = threadIdx.x;
  const int l = tid * 4;
  const int lm = l >> 4, lk = l & 15;
  const int bk = l >> 6, bn = l & 63;
  const int ty4 = (tid >> 4) * 4, tx4 = (tid & 15) * 4;
  float acc[4][4] = {};
  for (int k0 = 0; k0 < C; k0 += 16) {
    const ushort4 a4 = *(const ushort4*)(A + (size_t)(rt + lm) * C + k0 + lk);
    const float4 b4 = *(const float4*)(W + (size_t)(k0 + bk) * C + ct + bn);
    __syncthreads();
    As[lk + 0][lm] = __uint_as_float((unsigned)a4.x << 16);
    As[lk + 1][lm] = __uint_as_float((unsigned)a4.y << 16);
    As[lk + 2][lm] = __uint_as_float((unsigned)a4.z << 16);
    As[lk + 3][lm] = __uint_as_float((unsigned)a4.w << 16);
    *(float4*)&Bs[bk][bn] = b4;
    __syncthreads();
#pragma unroll
    for (int kk = 0; kk < 16; ++kk) {
      const float4 av = *(const float4*)&As[kk][ty4];
      const float4 bv = *(const float4*)&Bs[kk][tx4];
      const float a0[4] = {av.x, av.y, av.z, av.w};
      const float b0[4] = {bv.x, bv.y, bv.z, bv.w};
#pragma unroll
      for (int i = 0; i < 4; ++i)
#pragma unroll
        for (int j = 0; j < 4; ++j) acc[i][j] += a0[i] * b0[j];
    }
  }
#pragma unroll
  for (int i = 0; i < 4; ++i) {
    const int row = rt + ty4 + i;
#pragma unroll
    for (int j = 0; j < 4; ++j) {
      const int col = ct + tx4 + j;
      out[(size_t)row * C + col] = acc[i][j] + bias[col];
    }
  }
}

}  // namespace

extern "C" void kernel_launch(void* const* d_in, const int* in_sizes, int n_in,
                              void* d_out, int out_size, void* d_ws, size_t ws_size,
                              hipStream_t stream) {
  (void)in_sizes; (void)n_in; (void)out_size; (void)ws_size;
  const float* x      = (const float*)d_in[0];
  const float* w_qkv  = (const float*)d_in[1];
  const float* w_proj = (const float*)d_in[2];
  const float* b_proj = (const float*)d_in[3];
  const float* pos    = (const float*)d_in[4];
  float* out = (float*)d_out;

  char* p = (char*)d_ws;
  bf16* Qb = (bf16*)p;            p += (size_t)BHT * CHW * sizeof(bf16);   // 38.5 MB
  bf16* Kb = (bf16*)p;            p += (size_t)BHT * CHW * sizeof(bf16);   // 38.5 MB
  bf16* Vb = (bf16*)p;            p += (size_t)BHT * CHW * sizeof(bf16);   // 38.5 MB
  float* corr = (float*)p;        p += (size_t)BHT * DW2 * HW * sizeof(float); // 39.3 MB
  bf16* merged = (bf16*)p;        p += (size_t)NROWS * C * sizeof(bf16);   // 38.5 MB
  // total ws: ~193.5 MB

  gemm_qkv_scatter<<<dim3(C3 / 64, NROWS / 64), 256, 0, stream>>>(x, w_qkv, Qb, Kb, Vb);
  l2norm_ip<<<BHT, 256, 0, stream>>>(Qb);
  l2norm_ip<<<BHT, 256, 0, stream>>>(Kb);
  corr_kernel<<<BHT, 256, 0, stream>>>(Qb, Kb, pos, corr);
  app_kernel<<<dim3(BHT, 4), 256, 0, stream>>>(Qb, Kb, Vb, merged);
  motion_kernel<<<dim3(BHT, 4), 256, 0, stream>>>(corr, Vb, merged);
  gemm_proj<<<dim3(C / 64, NROWS / 64), 256, 0, stream>>>(merged, w_proj, b_proj, out);
}

// Round 3
// 1879.634 us; speedup vs baseline: 3.3789x; 3.3789x over previous
//
#include <hip/hip_runtime.h>
#include <hip/hip_bf16.h>

namespace {

constexpr int T = 8, WSP = 14, HW = 196;
constexpr int C = 768, NH = 8, HD = 96;
constexpr int NTOK = 1568;
constexpr int BHT = 1024;          // B*NH*T
constexpr int C3 = 2304;           // 3*C
constexpr int CHW = HD * HW;       // 18816
constexpr int NROWS = 25088;       // B*NTOK
constexpr int NT = 13;             // 16-row tiles covering 208 >= 196
constexpr int KW = 104;            // K_lds row stride (bf16 elems)
constexpr int VW = 232;            // Vt / P row stride
constexpr int UW = 72;             // corrT row stride

using bf16 = __hip_bfloat16;
typedef __attribute__((ext_vector_type(8))) short short8v;  // 8 x bf16 frag
typedef __attribute__((ext_vector_type(4))) float f32x4;

__device__ __forceinline__ float b2f(bf16 h) { return __bfloat162float(h); }
__device__ __forceinline__ bf16 f2b(float f) { return __float2bfloat16(f); }
__device__ __forceinline__ ushort b2u(bf16 h) { union { bf16 b; ushort u; } x; x.b = h; return x.u; }
__device__ __forceinline__ bf16 u2b(ushort u) { union { ushort u; bf16 b; } x; x.u = u; return x.b; }

// ---------------------------------------------------------------------------
// K1: QKV GEMM (25088 x 768) @ (768 x 2304) fp32, scatter bf16 to
// Q [bt][tok][c], K [bt][tok][c] (temporal shift on write), V [bt][c][hw].
// ---------------------------------------------------------------------------
__global__ __launch_bounds__(256) void gemm_qkv_scatter(
    const float* __restrict__ A, const float* __restrict__ W,
    bf16* __restrict__ Qo, bf16* __restrict__ Ko, bf16* __restrict__ Vo) {
  __shared__ __align__(16) float As[16][64];
  __shared__ __align__(16) float Bs[16][64];
  const int ct = blockIdx.x * 64;
  const int rt = blockIdx.y * 64;
  const int tid = threadIdx.x;
  const int l = tid * 4;
  const int lm = l >> 4, lk = l & 15;
  const int bk = l >> 6, bn = l & 63;
  const int ty4 = (tid >> 4) * 4, tx4 = (tid & 15) * 4;
  float acc[4][4] = {};
  for (int k0 = 0; k0 < C; k0 += 16) {
    const float4 a4 = *(const float4*)(A + (size_t)(rt + lm) * C + k0 + lk);
    const float4 b4 = *(const float4*)(W + (size_t)(k0 + bk) * C3 + ct + bn);
    __syncthreads();
    As[lk + 0][lm] = a4.x; As[lk + 1][lm] = a4.y;
    As[lk + 2][lm] = a4.z; As[lk + 3][lm] = a4.w;
    *(float4*)&Bs[bk][bn] = b4;
    __syncthreads();
#pragma unroll
    for (int kk = 0; kk < 16; ++kk) {
      const float4 av = *(const float4*)&As[kk][ty4];
      const float4 bv = *(const float4*)&Bs[kk][tx4];
      const float a0[4] = {av.x, av.y, av.z, av.w};
      const float b0[4] = {bv.x, bv.y, bv.z, bv.w};
#pragma unroll
      for (int i = 0; i < 4; ++i)
#pragma unroll
        for (int j = 0; j < 4; ++j) acc[i][j] += a0[i] * b0[j];
    }
  }
#pragma unroll
  for (int i = 0; i < 4; ++i) {
    const int row = rt + ty4 + i;
    const int b_ = row / NTOK, n = row % NTOK;
    const int t = n / HW, hw = n % HW;
#pragma unroll
    for (int j = 0; j < 4; ++j) {
      const int col = ct + tx4 + j;
      const bf16 v = f2b(acc[i][j]);
      const int s = col / C, rem = col % C;
      const int head = rem / HD, ch = rem % HD;
      const int bh = b_ * NH + head;
      if (s == 0) {
        Qo[(size_t)(bh * T + t) * CHW + hw * HD + ch] = v;
      } else if (s == 1) {
        if (t >= 1) Ko[(size_t)(bh * T + t - 1) * CHW + hw * HD + ch] = v;
        if (t == T - 1) Ko[(size_t)(bh * T + t) * CHW + hw * HD + ch] = v;
      } else {
        Vo[(size_t)(bh * T + t) * CHW + ch * HW + hw] = v;
      }
    }
  }
}

// ---------------------------------------------------------------------------
// K2: in-place l2norm over channel dim, X[bt][tok][c] rows. One wave per row.
// ---------------------------------------------------------------------------
__global__ __launch_bounds__(256) void l2norm_rows(bf16* __restrict__ X) {
  const int bt = blockIdx.x;
  const int w = threadIdx.x >> 6, lane = threadIdx.x & 63;
  bf16* base = X + (size_t)bt * CHW;
  for (int r = w; r < HW; r += 4) {
    float v0 = 0.f, v1 = 0.f;
    if (lane < 48) {
      const uint pk = *(const uint*)(base + r * HD + lane * 2);
      v0 = b2f(u2b((ushort)(pk & 0xffff)));
      v1 = b2f(u2b((ushort)(pk >> 16)));
    }
    float s = v0 * v0 + v1 * v1;
#pragma unroll
    for (int off = 32; off; off >>= 1) s += __shfl_xor(s, off);
    const float inv = 1.f / fmaxf(sqrtf(s), 1e-12f);
    if (lane < 48) {
      const uint o = ((uint)b2u(f2b(v0 * inv))) | (((uint)b2u(f2b(v1 * inv))) << 16);
      *(uint*)(base + r * HD + lane * 2) = o;
    }
  }
}

// ---------------------------------------------------------------------------
// K3: fused corr + appearance + motion attention per bt. 256 threads, 4 waves.
// MFMA 16x16x32 bf16 throughout. merged = 0.5*app + 0.5*motion (bf16).
// ---------------------------------------------------------------------------
__global__ __launch_bounds__(256) void fused_attn(
    const bf16* __restrict__ Qg, const bf16* __restrict__ Kg,
    const bf16* __restrict__ Vg, const float* __restrict__ pos,
    bf16* __restrict__ merged) {
  __shared__ __align__(16) bf16 Klds[208 * KW];    // 43,264 B  K tokens x ch
  __shared__ __align__(16) bf16 Vt[96 * VW];       // 44,544 B  V^T: ch x tok
  __shared__ __align__(16) bf16 corrT[208 * UW];   // 29,952 B  tok x disp(64pad)
  __shared__ __align__(16) bf16 P[4][16 * VW];     // 29,696 B  per-wave P band
  const int bt = blockIdx.x;
  const int tid = threadIdx.x;
  const int w = tid >> 6, lane = tid & 63;
  const int lr = lane & 15, lg = lane >> 4;

  // ---- P0: staging ----
  {
    const uint4* kg = (const uint4*)(Kg + (size_t)bt * CHW);  // 196 rows x 12
    uint4* kl = (uint4*)Klds;                                 // row = 13 uint4
    for (int i = tid; i < 196 * 12; i += 256) { const int r = i / 12, g = i - r * 12; kl[r * 13 + g] = kg[i]; }
    const uint4 z4 = make_uint4(0u, 0u, 0u, 0u);
    for (int i = tid; i < 12 * 13; i += 256) { const int r = 196 + i / 13, g = i % 13; kl[r * 13 + g] = z4; }
    const uint* vg = (const uint*)(Vg + (size_t)bt * CHW);    // 96 rows x 98 u32
    uint* vl = (uint*)Vt;                                     // row = 116 u32
    for (int i = tid; i < 96 * 98; i += 256) { const int c = i / 98, g = i - c * 98; vl[c * 116 + g] = vg[i]; }
    for (int i = tid; i < 96 * 18; i += 256) { const int c = i / 18, g = 98 + i % 18; vl[c * 116 + g] = 0u; }
    // corrT init = pos^T (bf16), zero padding
    uint* ct32 = (uint*)corrT;                                // row = 36 u32
    for (int i = tid; i < 208 * 36; i += 256) {
      const int n = i % 208, up = i / 208;
      const int u0 = 2 * up, u1 = u0 + 1;
      const float p0 = (n < 196 && u0 < 49) ? pos[u0 * 196 + n] : 0.f;
      const float p1 = (n < 196 && u1 < 49) ? pos[u1 * 196 + n] : 0.f;
      ct32[n * 36 + up] = ((uint)b2u(f2b(p0))) | (((uint)b2u(f2b(p1))) << 16);
    }
    // P pad cols [196..232) = 0 (K-padding of the PV contraction)
    uint* p32 = (uint*)P;
    for (int i = tid; i < 4 * 16 * 18; i += 256) { const int row = i / 18, g = 98 + i % 18; p32[row * 116 + g] = 0u; }
  }
  __syncthreads();

  const size_t qbase = (size_t)bt * CHW;

  // ---- P1: S tiles -> correlation extraction into corrT ----
  for (int rt = w; rt < NT; rt += 4) {
    const int rq = (rt * 16 + lr > 195) ? 195 : rt * 16 + lr;
    short8v qa[3];
#pragma unroll
    for (int kc = 0; kc < 3; ++kc)
      qa[kc] = *(const short8v*)(Qg + qbase + (size_t)rq * HD + kc * 32 + lg * 8);
    f32x4 sacc[NT];
#pragma unroll
    for (int mt = 0; mt < NT; ++mt) sacc[mt] = (f32x4){0.f, 0.f, 0.f, 0.f};
#pragma unroll
    for (int kc = 0; kc < 3; ++kc)
#pragma unroll
      for (int mt = 0; mt < NT; ++mt) {
        const short8v bf = *(const short8v*)&Klds[(mt * 16 + lr) * KW + kc * 32 + lg * 8];
        sacc[mt] = __builtin_amdgcn_mfma_f32_16x16x32_bf16(qa[kc], bf, sacc[mt], 0, 0, 0);
      }
#pragma unroll
    for (int j = 0; j < 4; ++j) {
      const int rowg = rt * 16 + lg * 4 + j;
      if (rowg < 196) {
        const int h = rowg / WSP, wq = rowg - (rowg / WSP) * WSP;
#pragma unroll
        for (int mt = 0; mt < NT; ++mt) {
          const int colg = mt * 16 + lr;
          if (colg < 196) {
            const int h2 = colg / WSP, w2 = colg - (colg / WSP) * WSP;
            const int dh = h2 - h + 3, dw = w2 - wq + 3;
            if (((unsigned)dh < 7u) && ((unsigned)dw < 7u)) {
              bf16* cp = &corrT[rowg * UW + dh * 7 + dw];
              *cp = f2b(b2f(*cp) + sacc[mt][j]);
            }
          }
        }
      }
    }
  }
  __syncthreads();

  // ---- P2: app softmax+PV, motion M+softmax+PV, merged store ----
  const int b_ = bt >> 6, head = (bt >> 3) & 7, tt = bt & 7;
  bf16* P_w = P[w];
  for (int rt = w; rt < NT; rt += 4) {
    // recompute S
    const int rq = (rt * 16 + lr > 195) ? 195 : rt * 16 + lr;
    short8v qa[3];
#pragma unroll
    for (int kc = 0; kc < 3; ++kc)
      qa[kc] = *(const short8v*)(Qg + qbase + (size_t)rq * HD + kc * 32 + lg * 8);
    f32x4 sacc[NT];
#pragma unroll
    for (int mt = 0; mt < NT; ++mt) sacc[mt] = (f32x4){0.f, 0.f, 0.f, 0.f};
#pragma unroll
    for (int kc = 0; kc < 3; ++kc)
#pragma unroll
      for (int mt = 0; mt < NT; ++mt) {
        const short8v bf = *(const short8v*)&Klds[(mt * 16 + lr) * KW + kc * 32 + lg * 8];
        sacc[mt] = __builtin_amdgcn_mfma_f32_16x16x32_bf16(qa[kc], bf, sacc[mt], 0, 0, 0);
      }
    // app softmax (x0.5) -> P band
#pragma unroll
    for (int j = 0; j < 4; ++j) {
      float mx = -1e30f;
#pragma unroll
      for (int mt = 0; mt < NT; ++mt) {
        float v = sacc[mt][j];
        if (mt == 12 && lr >= 4) v = -1e30f;
        mx = fmaxf(mx, v);
      }
      mx = fmaxf(mx, __shfl_xor(mx, 1)); mx = fmaxf(mx, __shfl_xor(mx, 2));
      mx = fmaxf(mx, __shfl_xor(mx, 4)); mx = fmaxf(mx, __shfl_xor(mx, 8));
      float e[NT], s = 0.f;
#pragma unroll
      for (int mt = 0; mt < NT; ++mt) {
        const float ee = (mt == 12 && lr >= 4) ? 0.f : __expf(sacc[mt][j] - mx);
        e[mt] = ee; s += ee;
      }
      s += __shfl_xor(s, 1); s += __shfl_xor(s, 2); s += __shfl_xor(s, 4); s += __shfl_xor(s, 8);
      const float sc = 0.5f / s;
      const int prow = lg * 4 + j;
#pragma unroll
      for (int mt = 0; mt < NT; ++mt)
        if (mt < 12 || lr < 4) P_w[prow * VW + mt * 16 + lr] = f2b(e[mt] * sc);
    }
    // app PV
    f32x4 pacc[6];
#pragma unroll
    for (int ct = 0; ct < 6; ++ct) pacc[ct] = (f32x4){0.f, 0.f, 0.f, 0.f};
    short8v pf[7];
#pragma unroll
    for (int kp = 0; kp < 7; ++kp) pf[kp] = *(const short8v*)&P_w[lr * VW + kp * 32 + lg * 8];
#pragma unroll
    for (int ct = 0; ct < 6; ++ct)
#pragma unroll
      for (int kp = 0; kp < 7; ++kp) {
        const short8v vf = *(const short8v*)&Vt[(ct * 16 + lr) * VW + kp * 32 + lg * 8];
        pacc[ct] = __builtin_amdgcn_mfma_f32_16x16x32_bf16(pf[kp], vf, pacc[ct], 0, 0, 0);
      }
    // motion scores M = corrT . corrT^T  (K = 64, zero-padded)
    f32x4 macc[NT];
#pragma unroll
    for (int mt = 0; mt < NT; ++mt) macc[mt] = (f32x4){0.f, 0.f, 0.f, 0.f};
    short8v ca[2];
#pragma unroll
    for (int kc = 0; kc < 2; ++kc)
      ca[kc] = *(const short8v*)&corrT[(rt * 16 + lr) * UW + kc * 32 + lg * 8];
#pragma unroll
    for (int kc = 0; kc < 2; ++kc)
#pragma unroll
      for (int mt = 0; mt < NT; ++mt) {
        const short8v cb = *(const short8v*)&corrT[(mt * 16 + lr) * UW + kc * 32 + lg * 8];
        macc[mt] = __builtin_amdgcn_mfma_f32_16x16x32_bf16(ca[kc], cb, macc[mt], 0, 0, 0);
      }
    // motion softmax (x0.5) -> P band (overwrite)
#pragma unroll
    for (int j = 0; j < 4; ++j) {
      float mx = -1e30f;
#pragma unroll
      for (int mt = 0; mt < NT; ++mt) {
        float v = macc[mt][j];
        if (mt == 12 && lr >= 4) v = -1e30f;
        mx = fmaxf(mx, v);
      }
      mx = fmaxf(mx, __shfl_xor(mx, 1)); mx = fmaxf(mx, __shfl_xor(mx, 2));
      mx = fmaxf(mx, __shfl_xor(mx, 4)); mx = fmaxf(mx, __shfl_xor(mx, 8));
      float e[NT], s = 0.f;
#pragma unroll
      for (int mt = 0; mt < NT; ++mt) {
        const float ee = (mt == 12 && lr >= 4) ? 0.f : __expf(macc[mt][j] - mx);
        e[mt] = ee; s += ee;
      }
      s += __shfl_xor(s, 1); s += __shfl_xor(s, 2); s += __shfl_xor(s, 4); s += __shfl_xor(s, 8);
      const float sc = 0.5f / s;
      const int prow = lg * 4 + j;
#pragma unroll
      for (int mt = 0; mt < NT; ++mt)
        if (mt < 12 || lr < 4) P_w[prow * VW + mt * 16 + lr] = f2b(e[mt] * sc);
    }
    // motion PV accumulates into pacc
#pragma unroll
    for (int kp = 0; kp < 7; ++kp) pf[kp] = *(const short8v*)&P_w[lr * VW + kp * 32 + lg * 8];
#pragma unroll
    for (int ct = 0; ct < 6; ++ct)
#pragma unroll
      for (int kp = 0; kp < 7; ++kp) {
        const short8v vf = *(const short8v*)&Vt[(ct * 16 + lr) * VW + kp * 32 + lg * 8];
        pacc[ct] = __builtin_amdgcn_mfma_f32_16x16x32_bf16(pf[kp], vf, pacc[ct], 0, 0, 0);
      }
    // store merged
#pragma unroll
    for (int j = 0; j < 4; ++j) {
      const int rowg = rt * 16 + lg * 4 + j;
      if (rowg < 196) {
        const size_t base = ((size_t)(b_ * NTOK + tt * HW + rowg)) * C + head * HD;
#pragma unroll
        for (int ct = 0; ct < 6; ++ct)
          merged[base + ct * 16 + lr] = f2b(pacc[ct][j]);
      }
    }
  }
}

// ---------------------------------------------------------------------------
// K4: proj GEMM (25088 x 768) bf16 @ (768 x 768) f32 + bias -> out f32
// ---------------------------------------------------------------------------
__global__ __launch_bounds__(256) void gemm_proj(
    const bf16* __restrict__ A, const float* __restrict__ W,
    const float* __restrict__ bias, float* __restrict__ out) {
  __shared__ __align__(16) float As[16][64];
  __shared__ __align__(16) float Bs[16][64];
  const int ct = blockIdx.x * 64;
  const int rt = blockIdx.y * 64;
  const int tid = threadIdx.x;
  const int l = tid * 4;
  const int lm = l >> 4, lk = l & 15;
  const int bk = l >> 6, bn = l & 63;
  const int ty4 = (tid >> 4) * 4, tx4 = (tid & 15) * 4;
  float acc[4][4] = {};
  for (int k0 = 0; k0 < C; k0 += 16) {
    const ushort4 a4 = *(const ushort4*)(A + (size_t)(rt + lm) * C + k0 + lk);
    const float4 b4 = *(const float4*)(W + (size_t)(k0 + bk) * C + ct + bn);
    __syncthreads();
    As[lk + 0][lm] = __uint_as_float((unsigned)a4.x << 16);
    As[lk + 1][lm] = __uint_as_float((unsigned)a4.y << 16);
    As[lk + 2][lm] = __uint_as_float((unsigned)a4.z << 16);
    As[lk + 3][lm] = __uint_as_float((unsigned)a4.w << 16);
    *(float4*)&Bs[bk][bn] = b4;
    __syncthreads();
#pragma unroll
    for (int kk = 0; kk < 16; ++kk) {
      const float4 av = *(const float4*)&As[kk][ty4];
      const float4 bv = *(const float4*)&Bs[kk][tx4];
      const float a0[4] = {av.x, av.y, av.z, av.w};
      const float b0[4] = {bv.x, bv.y, bv.z, bv.w};
#pragma unroll
      for (int i = 0; i < 4; ++i)
#pragma unroll
        for (int j = 0; j < 4; ++j) acc[i][j] += a0[i] * b0[j];
    }
  }
#pragma unroll
  for (int i = 0; i < 4; ++i) {
    const int row = rt + ty4 + i;
#pragma unroll
    for (int j = 0; j < 4; ++j) {
      const int col = ct + tx4 + j;
      out[(size_t)row * C + col] = acc[i][j] + bias[col];
    }
  }
}

}  // namespace

extern "C" void kernel_launch(void* const* d_in, const int* in_sizes, int n_in,
                              void* d_out, int out_size, void* d_ws, size_t ws_size,
                              hipStream_t stream) {
  (void)in_sizes; (void)n_in; (void)out_size; (void)ws_size;
  const float* x      = (const float*)d_in[0];
  const float* w_qkv  = (const float*)d_in[1];
  const float* w_proj = (const float*)d_in[2];
  const float* b_proj = (const float*)d_in[3];
  const float* pos    = (const float*)d_in[4];
  float* out = (float*)d_out;

  char* p = (char*)d_ws;
  bf16* Qb = (bf16*)p;     p += (size_t)BHT * CHW * sizeof(bf16);   // 38.5 MB
  bf16* Kb = (bf16*)p;     p += (size_t)BHT * CHW * sizeof(bf16);   // 38.5 MB
  bf16* Vb = (bf16*)p;     p += (size_t)BHT * CHW * sizeof(bf16);   // 38.5 MB
  bf16* merged = (bf16*)p; p += (size_t)NROWS * C * sizeof(bf16);   // 38.5 MB
  // total ws: ~154 MB

  gemm_qkv_scatter<<<dim3(C3 / 64, NROWS / 64), 256, 0, stream>>>(x, w_qkv, Qb, Kb, Vb);
  l2norm_rows<<<BHT, 256, 0, stream>>>(Qb);
  l2norm_rows<<<BHT, 256, 0, stream>>>(Kb);
  fused_attn<<<BHT, 256, 0, stream>>>(Qb, Kb, Vb, pos, merged);
  gemm_proj<<<dim3(C / 64, NROWS / 64), 256, 0, stream>>>(merged, w_proj, b_proj, out);
}

// Round 4
// 989.213 us; speedup vs baseline: 6.4204x; 1.9001x over previous
//
#include <hip/hip_runtime.h>
#include <hip/hip_bf16.h>

namespace {

constexpr int T = 8, WSP = 14, HW = 196;
constexpr int C = 768, NH = 8, HD = 96;
constexpr int NTOK = 1568;
constexpr int BHT = 1024;          // B*NH*T
constexpr int C3 = 2304;           // 3*C
constexpr int CHW = HD * HW;       // 18816
constexpr int NROWS = 25088;       // B*NTOK
constexpr int NT = 13;             // 16-row tiles covering 208 >= 196
constexpr int KW = 104;            // K_lds row stride (bf16 elems)
constexpr int VW = 232;            // Vt / P row stride
constexpr int UW = 72;             // corrT row stride

using bf16 = __hip_bfloat16;
typedef __attribute__((ext_vector_type(8))) short short8v;  // 8 x bf16 frag
typedef __attribute__((ext_vector_type(4))) float f32x4;

__device__ __forceinline__ float b2f(bf16 h) { return __bfloat162float(h); }
__device__ __forceinline__ bf16 f2b(float f) { return __float2bfloat16(f); }
__device__ __forceinline__ ushort b2u(bf16 h) { union { bf16 b; ushort u; } x; x.b = h; return x.u; }
__device__ __forceinline__ bf16 u2b(ushort u) { union { ushort u; bf16 b; } x; x.u = u; return x.b; }
__device__ __forceinline__ uint pk2(float lo, float hi) {
  return ((uint)b2u(f2b(hi)) << 16) | (uint)b2u(f2b(lo));
}

// ---------------------------------------------------------------------------
// K0a: elementwise f32 -> bf16 (8 elems / thread)
// ---------------------------------------------------------------------------
__global__ __launch_bounds__(256) void conv_to_bf16(
    const float* __restrict__ X, bf16* __restrict__ Y, int n8) {
  const int i = blockIdx.x * 256 + threadIdx.x;
  if (i >= n8) return;
  const float4 a = ((const float4*)X)[i * 2];
  const float4 b = ((const float4*)X)[i * 2 + 1];
  uint4 o;
  o.x = pk2(a.x, a.y); o.y = pk2(a.z, a.w);
  o.z = pk2(b.x, b.y); o.w = pk2(b.z, b.w);
  ((uint4*)Y)[i] = o;
}

// ---------------------------------------------------------------------------
// K0b: W [rows][cols] f32 -> Wt [cols][rows] bf16, 64x64 LDS tiles.
// ---------------------------------------------------------------------------
__global__ __launch_bounds__(256) void transpose_to_bf16(
    const float* __restrict__ W, bf16* __restrict__ Wt, int rows, int cols) {
  __shared__ __align__(16) bf16 Lt[64][72];
  const int r0 = blockIdx.y * 64, c0 = blockIdx.x * 64;
  const int tid = threadIdx.x;
  const int r = tid >> 2, q = (tid & 3) * 16;
  const float* src = W + (size_t)(r0 + r) * cols + c0 + q;
#pragma unroll
  for (int i = 0; i < 16; i += 4) {
    const float4 v = *(const float4*)(src + i);
    Lt[q + i + 0][r] = f2b(v.x);
    Lt[q + i + 1][r] = f2b(v.y);
    Lt[q + i + 2][r] = f2b(v.z);
    Lt[q + i + 3][r] = f2b(v.w);
  }
  __syncthreads();
  const int c = tid >> 2, kc = (tid & 3) * 16;
  uint4* dst = (uint4*)(Wt + (size_t)(c0 + c) * rows + r0 + kc);
  const uint4* srcl = (const uint4*)(&Lt[c][kc]);
  dst[0] = srcl[0];
  dst[1] = srcl[1];
}

// ---------------------------------------------------------------------------
// K1: QKV GEMM, bf16 MFMA. A=xb [25088][768], Bt=wqkvT [2304][768].
// Swapped-operand layout: acc[cj][ri] holds D[col][row]; lane: row-token=lr,
// 4 consecutive cols = lg*4+j. Scatter epilogue to Q/K(shifted)/V.
// ---------------------------------------------------------------------------
__global__ __launch_bounds__(256) void gemm_qkv_mfma(
    const bf16* __restrict__ A, const bf16* __restrict__ Bt,
    bf16* __restrict__ Qo, bf16* __restrict__ Ko, bf16* __restrict__ Vo) {
  __shared__ __align__(16) bf16 As[128 * 72];
  __shared__ __align__(16) bf16 Bs[128 * 72];
  const int tid = threadIdx.x;
  const int w = tid >> 6, lane = tid & 63;
  const int lr = lane & 15, lg = lane >> 4;
  const int wr = w >> 1, wc = w & 1;
  const int rt = blockIdx.y * 128, ct = blockIdx.x * 128;
  const int srow = tid >> 1, sg = (tid & 1) * 4;

  f32x4 acc[4][4];
#pragma unroll
  for (int i = 0; i < 4; ++i)
#pragma unroll
    for (int j = 0; j < 4; ++j) acc[i][j] = (f32x4){0.f, 0.f, 0.f, 0.f};

  uint4 pa0[4], pb0[4], pa1[4], pb1[4];

#define LOADT(k0, pa, pb)                                                  \
  {                                                                        \
    const uint4* ga = (const uint4*)(A + (size_t)(rt + srow) * 768 + (k0) + sg * 8); \
    const uint4* gb = (const uint4*)(Bt + (size_t)(ct + srow) * 768 + (k0) + sg * 8); \
    _Pragma("unroll") for (int i = 0; i < 4; ++i) { pa[i] = ga[i]; pb[i] = gb[i]; } \
  }
#define STORET(pa, pb)                                                     \
  {                                                                        \
    uint4* la = (uint4*)(As + srow * 72 + sg * 8);                         \
    uint4* lb = (uint4*)(Bs + srow * 72 + sg * 8);                         \
    _Pragma("unroll") for (int i = 0; i < 4; ++i) { la[i] = pa[i]; lb[i] = pb[i]; } \
  }
#define MFMAT()                                                            \
  {                                                                        \
    _Pragma("unroll") for (int kc = 0; kc < 2; ++kc) {                     \
      short8v xa[4], wb[4];                                                \
      _Pragma("unroll") for (int f = 0; f < 4; ++f) {                      \
        xa[f] = *(const short8v*)(As + (wr * 64 + f * 16 + lr) * 72 + kc * 32 + lg * 8); \
        wb[f] = *(const short8v*)(Bs + (wc * 64 + f * 16 + lr) * 72 + kc * 32 + lg * 8); \
      }                                                                    \
      _Pragma("unroll") for (int cj = 0; cj < 4; ++cj)                     \
        _Pragma("unroll") for (int ri = 0; ri < 4; ++ri)                   \
          acc[cj][ri] = __builtin_amdgcn_mfma_f32_16x16x32_bf16(wb[cj], xa[ri], acc[cj][ri], 0, 0, 0); \
    }                                                                      \
  }

  LOADT(0, pa0, pb0);
  for (int kt = 0; kt < 12; kt += 2) {
    __syncthreads();
    STORET(pa0, pb0);
    LOADT((kt + 1) * 64, pa1, pb1);
    __syncthreads();
    MFMAT();
    __syncthreads();
    STORET(pa1, pb1);
    if (kt + 2 < 12) { LOADT((kt + 2) * 64, pa0, pb0); }
    __syncthreads();
    MFMAT();
  }

  const int s = blockIdx.x / 6;  // block-uniform: which of q/k/v
#pragma unroll
  for (int ri = 0; ri < 4; ++ri) {
    const int row = rt + wr * 64 + ri * 16 + lr;
    const int b_ = row / NTOK, n = row % NTOK;
    const int t = n / HW, hw = n % HW;
#pragma unroll
    for (int cj = 0; cj < 4; ++cj) {
      const int colb = ct + wc * 64 + cj * 16 + lg * 4;
      const int rem = colb - s * C;
      const int head = rem / HD, chb = rem - head * HD;
      const int bh = b_ * NH + head;
      if (s == 0) {
        uint2 pk;
        pk.x = pk2(acc[cj][ri][0], acc[cj][ri][1]);
        pk.y = pk2(acc[cj][ri][2], acc[cj][ri][3]);
        *(uint2*)(Qo + (size_t)(bh * T + t) * CHW + hw * HD + chb) = pk;
      } else if (s == 1) {
        uint2 pk;
        pk.x = pk2(acc[cj][ri][0], acc[cj][ri][1]);
        pk.y = pk2(acc[cj][ri][2], acc[cj][ri][3]);
        if (t >= 1)
          *(uint2*)(Ko + (size_t)(bh * T + t - 1) * CHW + hw * HD + chb) = pk;
        if (t == T - 1)
          *(uint2*)(Ko + (size_t)(bh * T + t) * CHW + hw * HD + chb) = pk;
      } else {
#pragma unroll
        for (int j = 0; j < 4; ++j)
          Vo[(size_t)(bh * T + t) * CHW + (chb + j) * HW + hw] = f2b(acc[cj][ri][j]);
      }
    }
  }
}

// ---------------------------------------------------------------------------
// K4: proj GEMM, bf16 MFMA. A=merged [25088][768], Bt=wprojT [768][768].
// Swapped-operand layout -> float4 stores with bias.
// ---------------------------------------------------------------------------
__global__ __launch_bounds__(256) void gemm_proj_mfma(
    const bf16* __restrict__ A, const bf16* __restrict__ Bt,
    const float* __restrict__ bias, float* __restrict__ out) {
  __shared__ __align__(16) bf16 As[128 * 72];
  __shared__ __align__(16) bf16 Bs[128 * 72];
  const int tid = threadIdx.x;
  const int w = tid >> 6, lane = tid & 63;
  const int lr = lane & 15, lg = lane >> 4;
  const int wr = w >> 1, wc = w & 1;
  const int rt = blockIdx.y * 128, ct = blockIdx.x * 128;
  const int srow = tid >> 1, sg = (tid & 1) * 4;

  f32x4 acc[4][4];
#pragma unroll
  for (int i = 0; i < 4; ++i)
#pragma unroll
    for (int j = 0; j < 4; ++j) acc[i][j] = (f32x4){0.f, 0.f, 0.f, 0.f};

  uint4 pa0[4], pb0[4], pa1[4], pb1[4];

  LOADT(0, pa0, pb0);
  for (int kt = 0; kt < 12; kt += 2) {
    __syncthreads();
    STORET(pa0, pb0);
    LOADT((kt + 1) * 64, pa1, pb1);
    __syncthreads();
    MFMAT();
    __syncthreads();
    STORET(pa1, pb1);
    if (kt + 2 < 12) { LOADT((kt + 2) * 64, pa0, pb0); }
    __syncthreads();
    MFMAT();
  }

#pragma unroll
  for (int ri = 0; ri < 4; ++ri) {
    const int row = rt + wr * 64 + ri * 16 + lr;
#pragma unroll
    for (int cj = 0; cj < 4; ++cj) {
      const int colb = ct + wc * 64 + cj * 16 + lg * 4;
      const float4 bv = *(const float4*)(bias + colb);
      float4 o;
      o.x = acc[cj][ri][0] + bv.x;
      o.y = acc[cj][ri][1] + bv.y;
      o.z = acc[cj][ri][2] + bv.z;
      o.w = acc[cj][ri][3] + bv.w;
      *(float4*)(out + (size_t)row * C + colb) = o;
    }
  }
}

// ---------------------------------------------------------------------------
// K2: in-place l2norm over channel dim, X[bt][tok][c] rows. One wave per row.
// ---------------------------------------------------------------------------
__global__ __launch_bounds__(256) void l2norm_rows(bf16* __restrict__ X) {
  const int bt = blockIdx.x;
  const int w = threadIdx.x >> 6, lane = threadIdx.x & 63;
  bf16* base = X + (size_t)bt * CHW;
  for (int r = w; r < HW; r += 4) {
    float v0 = 0.f, v1 = 0.f;
    if (lane < 48) {
      const uint pk = *(const uint*)(base + r * HD + lane * 2);
      v0 = b2f(u2b((ushort)(pk & 0xffff)));
      v1 = b2f(u2b((ushort)(pk >> 16)));
    }
    float s = v0 * v0 + v1 * v1;
#pragma unroll
    for (int off = 32; off; off >>= 1) s += __shfl_xor(s, off);
    const float inv = 1.f / fmaxf(sqrtf(s), 1e-12f);
    if (lane < 48) {
      const uint o = ((uint)b2u(f2b(v0 * inv))) | (((uint)b2u(f2b(v1 * inv))) << 16);
      *(uint*)(base + r * HD + lane * 2) = o;
    }
  }
}

// ---------------------------------------------------------------------------
// K3: fused corr + appearance + motion attention per bt. 256 threads, 4 waves.
// ---------------------------------------------------------------------------
__global__ __launch_bounds__(256) void fused_attn(
    const bf16* __restrict__ Qg, const bf16* __restrict__ Kg,
    const bf16* __restrict__ Vg, const float* __restrict__ pos,
    bf16* __restrict__ merged) {
  __shared__ __align__(16) bf16 Klds[208 * KW];    // 43,264 B
  __shared__ __align__(16) bf16 Vt[96 * VW];       // 44,544 B
  __shared__ __align__(16) bf16 corrT[208 * UW];   // 29,952 B
  __shared__ __align__(16) bf16 P[4][16 * VW];     // 29,696 B
  const int bt = blockIdx.x;
  const int tid = threadIdx.x;
  const int w = tid >> 6, lane = tid & 63;
  const int lr = lane & 15, lg = lane >> 4;

  // ---- P0: staging ----
  {
    const uint4* kg = (const uint4*)(Kg + (size_t)bt * CHW);
    uint4* kl = (uint4*)Klds;
    for (int i = tid; i < 196 * 12; i += 256) { const int r = i / 12, g = i - r * 12; kl[r * 13 + g] = kg[i]; }
    const uint4 z4 = make_uint4(0u, 0u, 0u, 0u);
    for (int i = tid; i < 12 * 13; i += 256) { const int r = 196 + i / 13, g = i % 13; kl[r * 13 + g] = z4; }
    const uint* vg = (const uint*)(Vg + (size_t)bt * CHW);
    uint* vl = (uint*)Vt;
    for (int i = tid; i < 96 * 98; i += 256) { const int c = i / 98, g = i - c * 98; vl[c * 116 + g] = vg[i]; }
    for (int i = tid; i < 96 * 18; i += 256) { const int c = i / 18, g = 98 + i % 18; vl[c * 116 + g] = 0u; }
    uint* ct32 = (uint*)corrT;
    for (int i = tid; i < 208 * 36; i += 256) {
      const int n = i % 208, up = i / 208;
      const int u0 = 2 * up, u1 = u0 + 1;
      const float p0 = (n < 196 && u0 < 49) ? pos[u0 * 196 + n] : 0.f;
      const float p1 = (n < 196 && u1 < 49) ? pos[u1 * 196 + n] : 0.f;
      ct32[n * 36 + up] = ((uint)b2u(f2b(p0))) | (((uint)b2u(f2b(p1))) << 16);
    }
    uint* p32 = (uint*)P;
    for (int i = tid; i < 4 * 16 * 18; i += 256) { const int row = i / 18, g = 98 + i % 18; p32[row * 116 + g] = 0u; }
  }
  __syncthreads();

  const size_t qbase = (size_t)bt * CHW;

  // ---- P1: S tiles -> correlation extraction into corrT ----
  for (int rt = w; rt < NT; rt += 4) {
    const int rq = (rt * 16 + lr > 195) ? 195 : rt * 16 + lr;
    short8v qa[3];
#pragma unroll
    for (int kc = 0; kc < 3; ++kc)
      qa[kc] = *(const short8v*)(Qg + qbase + (size_t)rq * HD + kc * 32 + lg * 8);
    f32x4 sacc[NT];
#pragma unroll
    for (int mt = 0; mt < NT; ++mt) sacc[mt] = (f32x4){0.f, 0.f, 0.f, 0.f};
#pragma unroll
    for (int kc = 0; kc < 3; ++kc)
#pragma unroll
      for (int mt = 0; mt < NT; ++mt) {
        const short8v bf = *(const short8v*)&Klds[(mt * 16 + lr) * KW + kc * 32 + lg * 8];
        sacc[mt] = __builtin_amdgcn_mfma_f32_16x16x32_bf16(qa[kc], bf, sacc[mt], 0, 0, 0);
      }
#pragma unroll
    for (int j = 0; j < 4; ++j) {
      const int rowg = rt * 16 + lg * 4 + j;
      if (rowg < 196) {
        const int h = rowg / WSP, wq = rowg - (rowg / WSP) * WSP;
#pragma unroll
        for (int mt = 0; mt < NT; ++mt) {
          const int colg = mt * 16 + lr;
          if (colg < 196) {
            const int h2 = colg / WSP, w2 = colg - (colg / WSP) * WSP;
            const int dh = h2 - h + 3, dw = w2 - wq + 3;
            if (((unsigned)dh < 7u) && ((unsigned)dw < 7u)) {
              bf16* cp = &corrT[rowg * UW + dh * 7 + dw];
              *cp = f2b(b2f(*cp) + sacc[mt][j]);
            }
          }
        }
      }
    }
  }
  __syncthreads();

  // ---- P2: app softmax+PV, motion M+softmax+PV, merged store ----
  const int b_ = bt >> 6, head = (bt >> 3) & 7, tt = bt & 7;
  bf16* P_w = P[w];
  for (int rt = w; rt < NT; rt += 4) {
    const int rq = (rt * 16 + lr > 195) ? 195 : rt * 16 + lr;
    short8v qa[3];
#pragma unroll
    for (int kc = 0; kc < 3; ++kc)
      qa[kc] = *(const short8v*)(Qg + qbase + (size_t)rq * HD + kc * 32 + lg * 8);
    f32x4 sacc[NT];
#pragma unroll
    for (int mt = 0; mt < NT; ++mt) sacc[mt] = (f32x4){0.f, 0.f, 0.f, 0.f};
#pragma unroll
    for (int kc = 0; kc < 3; ++kc)
#pragma unroll
      for (int mt = 0; mt < NT; ++mt) {
        const short8v bf = *(const short8v*)&Klds[(mt * 16 + lr) * KW + kc * 32 + lg * 8];
        sacc[mt] = __builtin_amdgcn_mfma_f32_16x16x32_bf16(qa[kc], bf, sacc[mt], 0, 0, 0);
      }
#pragma unroll
    for (int j = 0; j < 4; ++j) {
      float mx = -1e30f;
#pragma unroll
      for (int mt = 0; mt < NT; ++mt) {
        float v = sacc[mt][j];
        if (mt == 12 && lr >= 4) v = -1e30f;
        mx = fmaxf(mx, v);
      }
      mx = fmaxf(mx, __shfl_xor(mx, 1)); mx = fmaxf(mx, __shfl_xor(mx, 2));
      mx = fmaxf(mx, __shfl_xor(mx, 4)); mx = fmaxf(mx, __shfl_xor(mx, 8));
      float e[NT], s = 0.f;
#pragma unroll
      for (int mt = 0; mt < NT; ++mt) {
        const float ee = (mt == 12 && lr >= 4) ? 0.f : __expf(sacc[mt][j] - mx);
        e[mt] = ee; s += ee;
      }
      s += __shfl_xor(s, 1); s += __shfl_xor(s, 2); s += __shfl_xor(s, 4); s += __shfl_xor(s, 8);
      const float sc = 0.5f / s;
      const int prow = lg * 4 + j;
#pragma unroll
      for (int mt = 0; mt < NT; ++mt)
        if (mt < 12 || lr < 4) P_w[prow * VW + mt * 16 + lr] = f2b(e[mt] * sc);
    }
    f32x4 pacc[6];
#pragma unroll
    for (int ct = 0; ct < 6; ++ct) pacc[ct] = (f32x4){0.f, 0.f, 0.f, 0.f};
    short8v pf[7];
#pragma unroll
    for (int kp = 0; kp < 7; ++kp) pf[kp] = *(const short8v*)&P_w[lr * VW + kp * 32 + lg * 8];
#pragma unroll
    for (int ct = 0; ct < 6; ++ct)
#pragma unroll
      for (int kp = 0; kp < 7; ++kp) {
        const short8v vf = *(const short8v*)&Vt[(ct * 16 + lr) * VW + kp * 32 + lg * 8];
        pacc[ct] = __builtin_amdgcn_mfma_f32_16x16x32_bf16(pf[kp], vf, pacc[ct], 0, 0, 0);
      }
    f32x4 macc[NT];
#pragma unroll
    for (int mt = 0; mt < NT; ++mt) macc[mt] = (f32x4){0.f, 0.f, 0.f, 0.f};
    short8v ca[2];
#pragma unroll
    for (int kc = 0; kc < 2; ++kc)
      ca[kc] = *(const short8v*)&corrT[(rt * 16 + lr) * UW + kc * 32 + lg * 8];
#pragma unroll
    for (int kc = 0; kc < 2; ++kc)
#pragma unroll
      for (int mt = 0; mt < NT; ++mt) {
        const short8v cb = *(const short8v*)&corrT[(mt * 16 + lr) * UW + kc * 32 + lg * 8];
        macc[mt] = __builtin_amdgcn_mfma_f32_16x16x32_bf16(ca[kc], cb, macc[mt], 0, 0, 0);
      }
#pragma unroll
    for (int j = 0; j < 4; ++j) {
      float mx = -1e30f;
#pragma unroll
      for (int mt = 0; mt < NT; ++mt) {
        float v = macc[mt][j];
        if (mt == 12 && lr >= 4) v = -1e30f;
        mx = fmaxf(mx, v);
      }
      mx = fmaxf(mx, __shfl_xor(mx, 1)); mx = fmaxf(mx, __shfl_xor(mx, 2));
      mx = fmaxf(mx, __shfl_xor(mx, 4)); mx = fmaxf(mx, __shfl_xor(mx, 8));
      float e[NT], s = 0.f;
#pragma unroll
      for (int mt = 0; mt < NT; ++mt) {
        const float ee = (mt == 12 && lr >= 4) ? 0.f : __expf(macc[mt][j] - mx);
        e[mt] = ee; s += ee;
      }
      s += __shfl_xor(s, 1); s += __shfl_xor(s, 2); s += __shfl_xor(s, 4); s += __shfl_xor(s, 8);
      const float sc = 0.5f / s;
      const int prow = lg * 4 + j;
#pragma unroll
      for (int mt = 0; mt < NT; ++mt)
        if (mt < 12 || lr < 4) P_w[prow * VW + mt * 16 + lr] = f2b(e[mt] * sc);
    }
#pragma unroll
    for (int kp = 0; kp < 7; ++kp) pf[kp] = *(const short8v*)&P_w[lr * VW + kp * 32 + lg * 8];
#pragma unroll
    for (int ct = 0; ct < 6; ++ct)
#pragma unroll
      for (int kp = 0; kp < 7; ++kp) {
        const short8v vf = *(const short8v*)&Vt[(ct * 16 + lr) * VW + kp * 32 + lg * 8];
        pacc[ct] = __builtin_amdgcn_mfma_f32_16x16x32_bf16(pf[kp], vf, pacc[ct], 0, 0, 0);
      }
#pragma unroll
    for (int j = 0; j < 4; ++j) {
      const int rowg = rt * 16 + lg * 4 + j;
      if (rowg < 196) {
        const size_t base = ((size_t)(b_ * NTOK + tt * HW + rowg)) * C + head * HD;
#pragma unroll
        for (int ct = 0; ct < 6; ++ct)
          merged[base + ct * 16 + lr] = f2b(pacc[ct][j]);
      }
    }
  }
}

}  // namespace

extern "C" void kernel_launch(void* const* d_in, const int* in_sizes, int n_in,
                              void* d_out, int out_size, void* d_ws, size_t ws_size,
                              hipStream_t stream) {
  (void)in_sizes; (void)n_in; (void)out_size; (void)ws_size;
  const float* x      = (const float*)d_in[0];
  const float* w_qkv  = (const float*)d_in[1];
  const float* w_proj = (const float*)d_in[2];
  const float* b_proj = (const float*)d_in[3];
  const float* pos    = (const float*)d_in[4];
  float* out = (float*)d_out;

  char* p = (char*)d_ws;
  bf16* Qb = (bf16*)p;      p += (size_t)BHT * CHW * sizeof(bf16);    // 38.5 MB
  bf16* Kb = (bf16*)p;      p += (size_t)BHT * CHW * sizeof(bf16);    // 38.5 MB
  bf16* Vb = (bf16*)p;      p += (size_t)BHT * CHW * sizeof(bf16);    // 38.5 MB
  bf16* xbm = (bf16*)p;     p += (size_t)NROWS * C * sizeof(bf16);    // 38.5 MB (xb, then merged)
  bf16* wqkvT = (bf16*)p;   p += (size_t)C3 * C * sizeof(bf16);       // 3.5 MB
  bf16* wprojT = (bf16*)p;  p += (size_t)C * C * sizeof(bf16);        // 1.2 MB
  // total ws: ~159 MB

  conv_to_bf16<<<(NROWS * C / 8 + 255) / 256, 256, 0, stream>>>(x, xbm, NROWS * C / 8);
  transpose_to_bf16<<<dim3(C3 / 64, C / 64), 256, 0, stream>>>(w_qkv, wqkvT, C, C3);
  transpose_to_bf16<<<dim3(C / 64, C / 64), 256, 0, stream>>>(w_proj, wprojT, C, C);
  gemm_qkv_mfma<<<dim3(C3 / 128, NROWS / 128), 256, 0, stream>>>(xbm, wqkvT, Qb, Kb, Vb);
  l2norm_rows<<<BHT, 256, 0, stream>>>(Qb);
  l2norm_rows<<<BHT, 256, 0, stream>>>(Kb);
  fused_attn<<<BHT, 256, 0, stream>>>(Qb, Kb, Vb, pos, xbm /*merged*/);
  gemm_proj_mfma<<<dim3(C / 128, NROWS / 128), 256, 0, stream>>>(xbm, wprojT, b_proj, out);
}

// Round 5
// 550.327 us; speedup vs baseline: 11.5406x; 1.7975x over previous
//
#include <hip/hip_runtime.h>
#include <hip/hip_bf16.h>

namespace {

constexpr int T = 8, WSP = 14, HW = 196;
constexpr int C = 768, NH = 8, HD = 96;
constexpr int NTOK = 1568;
constexpr int BHT = 1024;          // B*NH*T
constexpr int C3 = 2304;           // 3*C
constexpr int CHW = HD * HW;       // 18816
constexpr int NROWS = 25088;       // B*NTOK
constexpr int NT = 13;             // 16-row tiles covering 208 >= 196
constexpr int KW = 104;            // K_lds row stride (bf16 elems)
constexpr int VW = 232;            // Vt / P row stride
constexpr int UW = 72;             // corrT row stride

using bf16 = __hip_bfloat16;
typedef __attribute__((ext_vector_type(8))) short short8v;  // 8 x bf16 frag
typedef __attribute__((ext_vector_type(4))) float f32x4;

__device__ __forceinline__ float b2f(bf16 h) { return __bfloat162float(h); }
__device__ __forceinline__ bf16 f2b(float f) { return __float2bfloat16(f); }
__device__ __forceinline__ ushort b2u(bf16 h) { union { bf16 b; ushort u; } x; x.b = h; return x.u; }
__device__ __forceinline__ bf16 u2b(ushort u) { union { ushort u; bf16 b; } x; x.u = u; return x.b; }
__device__ __forceinline__ uint pk2(float lo, float hi) {
  return ((uint)b2u(f2b(hi)) << 16) | (uint)b2u(f2b(lo));
}
// async global->LDS, 16B per lane, lane scatter = base + lane*16
__device__ __forceinline__ void gload_lds16(const bf16* g, bf16* l) {
  __builtin_amdgcn_global_load_lds(
      (const __attribute__((address_space(1))) unsigned int*)g,
      (__attribute__((address_space(3))) unsigned int*)l, 16, 0, 0);
}

// ---------------------------------------------------------------------------
// K0a: elementwise f32 -> bf16 (8 elems / thread)
// ---------------------------------------------------------------------------
__global__ __launch_bounds__(256) void conv_to_bf16(
    const float* __restrict__ X, bf16* __restrict__ Y, int n8) {
  const int i = blockIdx.x * 256 + threadIdx.x;
  if (i >= n8) return;
  const float4 a = ((const float4*)X)[i * 2];
  const float4 b = ((const float4*)X)[i * 2 + 1];
  uint4 o;
  o.x = pk2(a.x, a.y); o.y = pk2(a.z, a.w);
  o.z = pk2(b.x, b.y); o.w = pk2(b.z, b.w);
  ((uint4*)Y)[i] = o;
}

// ---------------------------------------------------------------------------
// K0b: W [rows][cols] f32 -> Wt [cols][rows] bf16, 64x64 LDS tiles.
// ---------------------------------------------------------------------------
__global__ __launch_bounds__(256) void transpose_to_bf16(
    const float* __restrict__ W, bf16* __restrict__ Wt, int rows, int cols) {
  __shared__ __align__(16) bf16 Lt[64][72];
  const int r0 = blockIdx.y * 64, c0 = blockIdx.x * 64;
  const int tid = threadIdx.x;
  const int r = tid >> 2, q = (tid & 3) * 16;
  const float* src = W + (size_t)(r0 + r) * cols + c0 + q;
#pragma unroll
  for (int i = 0; i < 16; i += 4) {
    const float4 v = *(const float4*)(src + i);
    Lt[q + i + 0][r] = f2b(v.x);
    Lt[q + i + 1][r] = f2b(v.y);
    Lt[q + i + 2][r] = f2b(v.z);
    Lt[q + i + 3][r] = f2b(v.w);
  }
  __syncthreads();
  const int c = tid >> 2, kc = (tid & 3) * 16;
  uint4* dst = (uint4*)(Wt + (size_t)(c0 + c) * rows + r0 + kc);
  const uint4* srcl = (const uint4*)(&Lt[c][kc]);
  dst[0] = srcl[0];
  dst[1] = srcl[1];
}

// ---------------------------------------------------------------------------
// Shared 128x128xK=768 MFMA core (m97 structure): global_load_lds staging,
// single LDS buffer, 2 barriers per K-step. acc[cj][ri]: D[col][row] fragments
// (swapped operands): lane holds row-token lr, 4 consecutive cols lg*4+j.
// ---------------------------------------------------------------------------
__device__ __forceinline__ void gemm128_core(
    const bf16* __restrict__ A, const bf16* __restrict__ Bt,
    int rt, int ct, bf16* As, bf16* Bs, f32x4 acc[4][4]) {
  const int tid = threadIdx.x;
  const int w = tid >> 6, lane = tid & 63;
  const int lr = lane & 15, lg = lane >> 4;
  const int wr = w >> 1, wc = w & 1;
  // per-lane global source coords for the 4 chunks this wave stages
  const int crow = (lane >> 3);        // row within 8-row chunk
  const int cole = (lane & 7) * 8;     // col element within 64
#pragma unroll
  for (int i = 0; i < 4; ++i)
#pragma unroll
    for (int j = 0; j < 4; ++j) acc[i][j] = (f32x4){0.f, 0.f, 0.f, 0.f};

  for (int kt = 0; kt < 12; ++kt) {
    const int k0 = kt * 64;
    __syncthreads();
#pragma unroll
    for (int i = 0; i < 4; ++i) {
      const int chunk = w * 4 + i;           // 16 chunks of 8 rows
      const int row = chunk * 8 + crow;
      gload_lds16(A + (size_t)(rt + row) * 768 + k0 + cole, As + chunk * 512);
      gload_lds16(Bt + (size_t)(ct + row) * 768 + k0 + cole, Bs + chunk * 512);
    }
    __syncthreads();  // compiler emits vmcnt(0) drain before barrier
#pragma unroll
    for (int kc = 0; kc < 2; ++kc) {
      short8v xa[4], wb[4];
#pragma unroll
      for (int f = 0; f < 4; ++f) {
        xa[f] = *(const short8v*)(As + (wr * 64 + f * 16 + lr) * 64 + kc * 32 + lg * 8);
        wb[f] = *(const short8v*)(Bs + (wc * 64 + f * 16 + lr) * 64 + kc * 32 + lg * 8);
      }
#pragma unroll
      for (int cj = 0; cj < 4; ++cj)
#pragma unroll
        for (int ri = 0; ri < 4; ++ri)
          acc[cj][ri] = __builtin_amdgcn_mfma_f32_16x16x32_bf16(wb[cj], xa[ri], acc[cj][ri], 0, 0, 0);
    }
  }
}

// ---------------------------------------------------------------------------
// K1: QKV GEMM, scatter epilogue to Q / K(shifted) / V.
// grid: 3528 linear blocks = 18 col-tiles x 196 row-tiles, XCD-chunk swizzled.
// ---------------------------------------------------------------------------
__global__ __launch_bounds__(256) void gemm_qkv_mfma(
    const bf16* __restrict__ A, const bf16* __restrict__ Bt,
    bf16* __restrict__ Qo, bf16* __restrict__ Ko, bf16* __restrict__ Vo) {
  __shared__ __align__(16) bf16 As[128 * 64];
  __shared__ __align__(16) bf16 Bs[128 * 64];
  const int id = blockIdx.x;
  const int sw = (id & 7) * 441 + (id >> 3);   // 3528 = 8 * 441 (bijective)
  const int cti = sw % 18, rti = sw / 18;
  const int ct = cti * 128, rt = rti * 128;
  const int tid = threadIdx.x;
  const int w = tid >> 6, lane = tid & 63;
  const int lr = lane & 15, lg = lane >> 4;
  const int wr = w >> 1, wc = w & 1;

  f32x4 acc[4][4];
  gemm128_core(A, Bt, rt, ct, As, Bs, acc);

  const int s = cti / 6;  // block-uniform: q / k / v
#pragma unroll
  for (int ri = 0; ri < 4; ++ri) {
    const int row = rt + wr * 64 + ri * 16 + lr;
    const int b_ = row / NTOK, n = row % NTOK;
    const int t = n / HW, hw = n % HW;
#pragma unroll
    for (int cj = 0; cj < 4; ++cj) {
      const int colb = ct + wc * 64 + cj * 16 + lg * 4;
      const int rem = colb - s * C;
      const int head = rem / HD, chb = rem - head * HD;
      const int bh = b_ * NH + head;
      if (s == 0) {
        uint2 pk;
        pk.x = pk2(acc[cj][ri][0], acc[cj][ri][1]);
        pk.y = pk2(acc[cj][ri][2], acc[cj][ri][3]);
        *(uint2*)(Qo + (size_t)(bh * T + t) * CHW + hw * HD + chb) = pk;
      } else if (s == 1) {
        uint2 pk;
        pk.x = pk2(acc[cj][ri][0], acc[cj][ri][1]);
        pk.y = pk2(acc[cj][ri][2], acc[cj][ri][3]);
        if (t >= 1)
          *(uint2*)(Ko + (size_t)(bh * T + t - 1) * CHW + hw * HD + chb) = pk;
        if (t == T - 1)
          *(uint2*)(Ko + (size_t)(bh * T + t) * CHW + hw * HD + chb) = pk;
      } else {
#pragma unroll
        for (int j = 0; j < 4; ++j)
          Vo[(size_t)(bh * T + t) * CHW + (chb + j) * HW + hw] = f2b(acc[cj][ri][j]);
      }
    }
  }
}

// ---------------------------------------------------------------------------
// K4: proj GEMM + bias -> out f32. grid: 1176 = 6 x 196, XCD-chunk swizzled.
// ---------------------------------------------------------------------------
__global__ __launch_bounds__(256) void gemm_proj_mfma(
    const bf16* __restrict__ A, const bf16* __restrict__ Bt,
    const float* __restrict__ bias, float* __restrict__ out) {
  __shared__ __align__(16) bf16 As[128 * 64];
  __shared__ __align__(16) bf16 Bs[128 * 64];
  const int id = blockIdx.x;
  const int sw = (id & 7) * 147 + (id >> 3);   // 1176 = 8 * 147 (bijective)
  const int cti = sw % 6, rti = sw / 6;
  const int ct = cti * 128, rt = rti * 128;
  const int tid = threadIdx.x;
  const int w = tid >> 6, lane = tid & 63;
  const int lr = lane & 15, lg = lane >> 4;
  const int wr = w >> 1, wc = w & 1;

  f32x4 acc[4][4];
  gemm128_core(A, Bt, rt, ct, As, Bs, acc);

#pragma unroll
  for (int ri = 0; ri < 4; ++ri) {
    const int row = rt + wr * 64 + ri * 16 + lr;
#pragma unroll
    for (int cj = 0; cj < 4; ++cj) {
      const int colb = ct + wc * 64 + cj * 16 + lg * 4;
      const float4 bv = *(const float4*)(bias + colb);
      float4 o;
      o.x = acc[cj][ri][0] + bv.x;
      o.y = acc[cj][ri][1] + bv.y;
      o.z = acc[cj][ri][2] + bv.z;
      o.w = acc[cj][ri][3] + bv.w;
      *(float4*)(out + (size_t)row * C + colb) = o;
    }
  }
}

// ---------------------------------------------------------------------------
// K2: in-place l2norm over channel dim, X[bt][tok][c] rows. One wave per row.
// ---------------------------------------------------------------------------
__global__ __launch_bounds__(256) void l2norm_rows(bf16* __restrict__ X) {
  const int bt = blockIdx.x;
  const int w = threadIdx.x >> 6, lane = threadIdx.x & 63;
  bf16* base = X + (size_t)bt * CHW;
  for (int r = w; r < HW; r += 4) {
    float v0 = 0.f, v1 = 0.f;
    if (lane < 48) {
      const uint pk = *(const uint*)(base + r * HD + lane * 2);
      v0 = b2f(u2b((ushort)(pk & 0xffff)));
      v1 = b2f(u2b((ushort)(pk >> 16)));
    }
    float s = v0 * v0 + v1 * v1;
#pragma unroll
    for (int off = 32; off; off >>= 1) s += __shfl_xor(s, off);
    const float inv = 1.f / fmaxf(sqrtf(s), 1e-12f);
    if (lane < 48) {
      const uint o = ((uint)b2u(f2b(v0 * inv))) | (((uint)b2u(f2b(v1 * inv))) << 16);
      *(uint*)(base + r * HD + lane * 2) = o;
    }
  }
}

// ---------------------------------------------------------------------------
// K3: fused corr + appearance + motion attention per bt. 256 threads, 4 waves.
// ---------------------------------------------------------------------------
__global__ __launch_bounds__(256) void fused_attn(
    const bf16* __restrict__ Qg, const bf16* __restrict__ Kg,
    const bf16* __restrict__ Vg, const float* __restrict__ pos,
    bf16* __restrict__ merged) {
  __shared__ __align__(16) bf16 Klds[208 * KW];    // 43,264 B
  __shared__ __align__(16) bf16 Vt[96 * VW];       // 44,544 B
  __shared__ __align__(16) bf16 corrT[208 * UW];   // 29,952 B
  __shared__ __align__(16) bf16 P[4][16 * VW];     // 29,696 B
  const int bt = blockIdx.x;
  const int tid = threadIdx.x;
  const int w = tid >> 6, lane = tid & 63;
  const int lr = lane & 15, lg = lane >> 4;

  // ---- P0: staging ----
  {
    const uint4* kg = (const uint4*)(Kg + (size_t)bt * CHW);
    uint4* kl = (uint4*)Klds;
    for (int i = tid; i < 196 * 12; i += 256) { const int r = i / 12, g = i - r * 12; kl[r * 13 + g] = kg[i]; }
    const uint4 z4 = make_uint4(0u, 0u, 0u, 0u);
    for (int i = tid; i < 12 * 13; i += 256) { const int r = 196 + i / 13, g = i % 13; kl[r * 13 + g] = z4; }
    const uint* vg = (const uint*)(Vg + (size_t)bt * CHW);
    uint* vl = (uint*)Vt;
    for (int i = tid; i < 96 * 98; i += 256) { const int c = i / 98, g = i - c * 98; vl[c * 116 + g] = vg[i]; }
    for (int i = tid; i < 96 * 18; i += 256) { const int c = i / 18, g = 98 + i % 18; vl[c * 116 + g] = 0u; }
    uint* ct32 = (uint*)corrT;
    for (int i = tid; i < 208 * 36; i += 256) {
      const int n = i % 208, up = i / 208;
      const int u0 = 2 * up, u1 = u0 + 1;
      const float p0 = (n < 196 && u0 < 49) ? pos[u0 * 196 + n] : 0.f;
      const float p1 = (n < 196 && u1 < 49) ? pos[u1 * 196 + n] : 0.f;
      ct32[n * 36 + up] = ((uint)b2u(f2b(p0))) | (((uint)b2u(f2b(p1))) << 16);
    }
    uint* p32 = (uint*)P;
    for (int i = tid; i < 4 * 16 * 18; i += 256) { const int row = i / 18, g = 98 + i % 18; p32[row * 116 + g] = 0u; }
  }
  __syncthreads();

  const size_t qbase = (size_t)bt * CHW;

  // ---- P1: S tiles -> correlation extraction into corrT ----
  for (int rt = w; rt < NT; rt += 4) {
    const int rq = (rt * 16 + lr > 195) ? 195 : rt * 16 + lr;
    short8v qa[3];
#pragma unroll
    for (int kc = 0; kc < 3; ++kc)
      qa[kc] = *(const short8v*)(Qg + qbase + (size_t)rq * HD + kc * 32 + lg * 8);
    f32x4 sacc[NT];
#pragma unroll
    for (int mt = 0; mt < NT; ++mt) sacc[mt] = (f32x4){0.f, 0.f, 0.f, 0.f};
#pragma unroll
    for (int kc = 0; kc < 3; ++kc)
#pragma unroll
      for (int mt = 0; mt < NT; ++mt) {
        const short8v bf = *(const short8v*)&Klds[(mt * 16 + lr) * KW + kc * 32 + lg * 8];
        sacc[mt] = __builtin_amdgcn_mfma_f32_16x16x32_bf16(qa[kc], bf, sacc[mt], 0, 0, 0);
      }
#pragma unroll
    for (int j = 0; j < 4; ++j) {
      const int rowg = rt * 16 + lg * 4 + j;
      if (rowg < 196) {
        const int h = rowg / WSP, wq = rowg - (rowg / WSP) * WSP;
#pragma unroll
        for (int mt = 0; mt < NT; ++mt) {
          const int colg = mt * 16 + lr;
          if (colg < 196) {
            const int h2 = colg / WSP, w2 = colg - (colg / WSP) * WSP;
            const int dh = h2 - h + 3, dw = w2 - wq + 3;
            if (((unsigned)dh < 7u) && ((unsigned)dw < 7u)) {
              bf16* cp = &corrT[rowg * UW + dh * 7 + dw];
              *cp = f2b(b2f(*cp) + sacc[mt][j]);
            }
          }
        }
      }
    }
  }
  __syncthreads();

  // ---- P2: app softmax+PV, motion M+softmax+PV, merged store ----
  const int b_ = bt >> 6, head = (bt >> 3) & 7, tt = bt & 7;
  bf16* P_w = P[w];
  for (int rt = w; rt < NT; rt += 4) {
    const int rq = (rt * 16 + lr > 195) ? 195 : rt * 16 + lr;
    short8v qa[3];
#pragma unroll
    for (int kc = 0; kc < 3; ++kc)
      qa[kc] = *(const short8v*)(Qg + qbase + (size_t)rq * HD + kc * 32 + lg * 8);
    f32x4 sacc[NT];
#pragma unroll
    for (int mt = 0; mt < NT; ++mt) sacc[mt] = (f32x4){0.f, 0.f, 0.f, 0.f};
#pragma unroll
    for (int kc = 0; kc < 3; ++kc)
#pragma unroll
      for (int mt = 0; mt < NT; ++mt) {
        const short8v bf = *(const short8v*)&Klds[(mt * 16 + lr) * KW + kc * 32 + lg * 8];
        sacc[mt] = __builtin_amdgcn_mfma_f32_16x16x32_bf16(qa[kc], bf, sacc[mt], 0, 0, 0);
      }
#pragma unroll
    for (int j = 0; j < 4; ++j) {
      float mx = -1e30f;
#pragma unroll
      for (int mt = 0; mt < NT; ++mt) {
        float v = sacc[mt][j];
        if (mt == 12 && lr >= 4) v = -1e30f;
        mx = fmaxf(mx, v);
      }
      mx = fmaxf(mx, __shfl_xor(mx, 1)); mx = fmaxf(mx, __shfl_xor(mx, 2));
      mx = fmaxf(mx, __shfl_xor(mx, 4)); mx = fmaxf(mx, __shfl_xor(mx, 8));
      float e[NT], s = 0.f;
#pragma unroll
      for (int mt = 0; mt < NT; ++mt) {
        const float ee = (mt == 12 && lr >= 4) ? 0.f : __expf(sacc[mt][j] - mx);
        e[mt] = ee; s += ee;
      }
      s += __shfl_xor(s, 1); s += __shfl_xor(s, 2); s += __shfl_xor(s, 4); s += __shfl_xor(s, 8);
      const float sc = 0.5f / s;
      const int prow = lg * 4 + j;
#pragma unroll
      for (int mt = 0; mt < NT; ++mt)
        if (mt < 12 || lr < 4) P_w[prow * VW + mt * 16 + lr] = f2b(e[mt] * sc);
    }
    f32x4 pacc[6];
#pragma unroll
    for (int ct = 0; ct < 6; ++ct) pacc[ct] = (f32x4){0.f, 0.f, 0.f, 0.f};
    short8v pf[7];
#pragma unroll
    for (int kp = 0; kp < 7; ++kp) pf[kp] = *(const short8v*)&P_w[lr * VW + kp * 32 + lg * 8];
#pragma unroll
    for (int ct = 0; ct < 6; ++ct)
#pragma unroll
      for (int kp = 0; kp < 7; ++kp) {
        const short8v vf = *(const short8v*)&Vt[(ct * 16 + lr) * VW + kp * 32 + lg * 8];
        pacc[ct] = __builtin_amdgcn_mfma_f32_16x16x32_bf16(pf[kp], vf, pacc[ct], 0, 0, 0);
      }
    f32x4 macc[NT];
#pragma unroll
    for (int mt = 0; mt < NT; ++mt) macc[mt] = (f32x4){0.f, 0.f, 0.f, 0.f};
    short8v ca[2];
#pragma unroll
    for (int kc = 0; kc < 2; ++kc)
      ca[kc] = *(const short8v*)&corrT[(rt * 16 + lr) * UW + kc * 32 + lg * 8];
#pragma unroll
    for (int kc = 0; kc < 2; ++kc)
#pragma unroll
      for (int mt = 0; mt < NT; ++mt) {
        const short8v cb = *(const short8v*)&corrT[(mt * 16 + lr) * UW + kc * 32 + lg * 8];
        macc[mt] = __builtin_amdgcn_mfma_f32_16x16x32_bf16(ca[kc], cb, macc[mt], 0, 0, 0);
      }
#pragma unroll
    for (int j = 0; j < 4; ++j) {
      float mx = -1e30f;
#pragma unroll
      for (int mt = 0; mt < NT; ++mt) {
        float v = macc[mt][j];
        if (mt == 12 && lr >= 4) v = -1e30f;
        mx = fmaxf(mx, v);
      }
      mx = fmaxf(mx, __shfl_xor(mx, 1)); mx = fmaxf(mx, __shfl_xor(mx, 2));
      mx = fmaxf(mx, __shfl_xor(mx, 4)); mx = fmaxf(mx, __shfl_xor(mx, 8));
      float e[NT], s = 0.f;
#pragma unroll
      for (int mt = 0; mt < NT; ++mt) {
        const float ee = (mt == 12 && lr >= 4) ? 0.f : __expf(macc[mt][j] - mx);
        e[mt] = ee; s += ee;
      }
      s += __shfl_xor(s, 1); s += __shfl_xor(s, 2); s += __shfl_xor(s, 4); s += __shfl_xor(s, 8);
      const float sc = 0.5f / s;
      const int prow = lg * 4 + j;
#pragma unroll
      for (int mt = 0; mt < NT; ++mt)
        if (mt < 12 || lr < 4) P_w[prow * VW + mt * 16 + lr] = f2b(e[mt] * sc);
    }
#pragma unroll
    for (int kp = 0; kp < 7; ++kp) pf[kp] = *(const short8v*)&P_w[lr * VW + kp * 32 + lg * 8];
#pragma unroll
    for (int ct = 0; ct < 6; ++ct)
#pragma unroll
      for (int kp = 0; kp < 7; ++kp) {
        const short8v vf = *(const short8v*)&Vt[(ct * 16 + lr) * VW + kp * 32 + lg * 8];
        pacc[ct] = __builtin_amdgcn_mfma_f32_16x16x32_bf16(pf[kp], vf, pacc[ct], 0, 0, 0);
      }
#pragma unroll
    for (int j = 0; j < 4; ++j) {
      const int rowg = rt * 16 + lg * 4 + j;
      if (rowg < 196) {
        const size_t base = ((size_t)(b_ * NTOK + tt * HW + rowg)) * C + head * HD;
#pragma unroll
        for (int ct = 0; ct < 6; ++ct)
          merged[base + ct * 16 + lr] = f2b(pacc[ct][j]);
      }
    }
  }
}

}  // namespace

extern "C" void kernel_launch(void* const* d_in, const int* in_sizes, int n_in,
                              void* d_out, int out_size, void* d_ws, size_t ws_size,
                              hipStream_t stream) {
  (void)in_sizes; (void)n_in; (void)out_size; (void)ws_size;
  const float* x      = (const float*)d_in[0];
  const float* w_qkv  = (const float*)d_in[1];
  const float* w_proj = (const float*)d_in[2];
  const float* b_proj = (const float*)d_in[3];
  const float* pos    = (const float*)d_in[4];
  float* out = (float*)d_out;

  char* p = (char*)d_ws;
  bf16* Qb = (bf16*)p;      p += (size_t)BHT * CHW * sizeof(bf16);    // 38.5 MB
  bf16* Kb = (bf16*)p;      p += (size_t)BHT * CHW * sizeof(bf16);    // 38.5 MB
  bf16* Vb = (bf16*)p;      p += (size_t)BHT * CHW * sizeof(bf16);    // 38.5 MB
  bf16* xbm = (bf16*)p;     p += (size_t)NROWS * C * sizeof(bf16);    // 38.5 MB (xb, then merged)
  bf16* wqkvT = (bf16*)p;   p += (size_t)C3 * C * sizeof(bf16);       // 3.5 MB
  bf16* wprojT = (bf16*)p;  p += (size_t)C * C * sizeof(bf16);        // 1.2 MB
  // total ws: ~159 MB

  conv_to_bf16<<<(NROWS * C / 8 + 255) / 256, 256, 0, stream>>>(x, xbm, NROWS * C / 8);
  transpose_to_bf16<<<dim3(C3 / 64, C / 64), 256, 0, stream>>>(w_qkv, wqkvT, C, C3);
  transpose_to_bf16<<<dim3(C / 64, C / 64), 256, 0, stream>>>(w_proj, wprojT, C, C);
  gemm_qkv_mfma<<<3528, 256, 0, stream>>>(xbm, wqkvT, Qb, Kb, Vb);
  l2norm_rows<<<BHT, 256, 0, stream>>>(Qb);
  l2norm_rows<<<BHT, 256, 0, stream>>>(Kb);
  fused_attn<<<BHT, 256, 0, stream>>>(Qb, Kb, Vb, pos, xbm /*merged*/);
  gemm_proj_mfma<<<1176, 256, 0, stream>>>(xbm, wprojT, b_proj, out);
}

// Round 6
// 497.988 us; speedup vs baseline: 12.7535x; 1.1051x over previous
//
#include <hip/hip_runtime.h>
#include <hip/hip_bf16.h>

namespace {

constexpr int T = 8, WSP = 14, HW = 196;
constexpr int C = 768, NH = 8, HD = 96;
constexpr int NTOK = 1568;
constexpr int BHT = 1024;          // B*NH*T
constexpr int C3 = 2304;           // 3*C
constexpr int CHW = HD * HW;       // 18816
constexpr int NROWS = 25088;       // B*NTOK
constexpr int NT = 13;             // 16-row tiles covering 208 >= 196
constexpr int VW = 232;            // Vt / P row stride
constexpr int UW = 72;             // corrT row stride

using bf16 = __hip_bfloat16;
typedef __attribute__((ext_vector_type(8))) short short8v;  // 8 x bf16 frag
typedef __attribute__((ext_vector_type(4))) float f32x4;

__device__ __forceinline__ float b2f(bf16 h) { return __bfloat162float(h); }
__device__ __forceinline__ bf16 f2b(float f) { return __float2bfloat16(f); }
__device__ __forceinline__ ushort b2u(bf16 h) { union { bf16 b; ushort u; } x; x.b = h; return x.u; }
__device__ __forceinline__ bf16 u2b(ushort u) { union { ushort u; bf16 b; } x; x.u = u; return x.b; }
__device__ __forceinline__ uint pk2(float lo, float hi) {
  return ((uint)b2u(f2b(hi)) << 16) | (uint)b2u(f2b(lo));
}
// async global->LDS, 16B per lane, lane scatter = base + lane*16
__device__ __forceinline__ void gload_lds16(const bf16* g, bf16* l) {
  __builtin_amdgcn_global_load_lds(
      (const __attribute__((address_space(1))) unsigned int*)g,
      (__attribute__((address_space(3))) unsigned int*)l, 16, 0, 0);
}

// ---------------------------------------------------------------------------
// K0a: elementwise f32 -> bf16 (8 elems / thread)
// ---------------------------------------------------------------------------
__global__ __launch_bounds__(256) void conv_to_bf16(
    const float* __restrict__ X, bf16* __restrict__ Y, int n8) {
  const int i = blockIdx.x * 256 + threadIdx.x;
  if (i >= n8) return;
  const float4 a = ((const float4*)X)[i * 2];
  const float4 b = ((const float4*)X)[i * 2 + 1];
  uint4 o;
  o.x = pk2(a.x, a.y); o.y = pk2(a.z, a.w);
  o.z = pk2(b.x, b.y); o.w = pk2(b.z, b.w);
  ((uint4*)Y)[i] = o;
}

// ---------------------------------------------------------------------------
// K0b: W [rows][cols] f32 -> Wt [cols][rows] bf16, 64x64 LDS tiles.
// ---------------------------------------------------------------------------
__global__ __launch_bounds__(256) void transpose_to_bf16(
    const float* __restrict__ W, bf16* __restrict__ Wt, int rows, int cols) {
  __shared__ __align__(16) bf16 Lt[64][72];
  const int r0 = blockIdx.y * 64, c0 = blockIdx.x * 64;
  const int tid = threadIdx.x;
  const int r = tid >> 2, q = (tid & 3) * 16;
  const float* src = W + (size_t)(r0 + r) * cols + c0 + q;
#pragma unroll
  for (int i = 0; i < 16; i += 4) {
    const float4 v = *(const float4*)(src + i);
    Lt[q + i + 0][r] = f2b(v.x);
    Lt[q + i + 1][r] = f2b(v.y);
    Lt[q + i + 2][r] = f2b(v.z);
    Lt[q + i + 3][r] = f2b(v.w);
  }
  __syncthreads();
  const int c = tid >> 2, kc = (tid & 3) * 16;
  uint4* dst = (uint4*)(Wt + (size_t)(c0 + c) * rows + r0 + kc);
  const uint4* srcl = (const uint4*)(&Lt[c][kc]);
  dst[0] = srcl[0];
  dst[1] = srcl[1];
}

// ---------------------------------------------------------------------------
// Shared 128x128xK=768 MFMA core (m97 structure): global_load_lds staging,
// single LDS buffer, 2 barriers per K-step. acc[cj][ri]: D[col][row] fragments
// (swapped operands): lane holds row-token lr, 4 consecutive cols lg*4+j.
// ---------------------------------------------------------------------------
__device__ __forceinline__ void gemm128_core(
    const bf16* __restrict__ A, const bf16* __restrict__ Bt,
    int rt, int ct, bf16* As, bf16* Bs, f32x4 acc[4][4]) {
  const int tid = threadIdx.x;
  const int w = tid >> 6, lane = tid & 63;
  const int lr = lane & 15, lg = lane >> 4;
  const int wr = w >> 1, wc = w & 1;
  const int crow = (lane >> 3);        // row within 8-row chunk
  const int cole = (lane & 7) * 8;     // col element within 64
#pragma unroll
  for (int i = 0; i < 4; ++i)
#pragma unroll
    for (int j = 0; j < 4; ++j) acc[i][j] = (f32x4){0.f, 0.f, 0.f, 0.f};

  for (int kt = 0; kt < 12; ++kt) {
    const int k0 = kt * 64;
    __syncthreads();
#pragma unroll
    for (int i = 0; i < 4; ++i) {
      const int chunk = w * 4 + i;           // 16 chunks of 8 rows
      const int row = chunk * 8 + crow;
      gload_lds16(A + (size_t)(rt + row) * 768 + k0 + cole, As + chunk * 512);
      gload_lds16(Bt + (size_t)(ct + row) * 768 + k0 + cole, Bs + chunk * 512);
    }
    __syncthreads();
#pragma unroll
    for (int kc = 0; kc < 2; ++kc) {
      short8v xa[4], wb[4];
#pragma unroll
      for (int f = 0; f < 4; ++f) {
        xa[f] = *(const short8v*)(As + (wr * 64 + f * 16 + lr) * 64 + kc * 32 + lg * 8);
        wb[f] = *(const short8v*)(Bs + (wc * 64 + f * 16 + lr) * 64 + kc * 32 + lg * 8);
      }
#pragma unroll
      for (int cj = 0; cj < 4; ++cj)
#pragma unroll
        for (int ri = 0; ri < 4; ++ri)
          acc[cj][ri] = __builtin_amdgcn_mfma_f32_16x16x32_bf16(wb[cj], xa[ri], acc[cj][ri], 0, 0, 0);
    }
  }
}

// ---------------------------------------------------------------------------
// K1: QKV GEMM, scatter epilogue to Q / K(shifted) / V.
// ---------------------------------------------------------------------------
__global__ __launch_bounds__(256) void gemm_qkv_mfma(
    const bf16* __restrict__ A, const bf16* __restrict__ Bt,
    bf16* __restrict__ Qo, bf16* __restrict__ Ko, bf16* __restrict__ Vo) {
  __shared__ __align__(16) bf16 As[128 * 64];
  __shared__ __align__(16) bf16 Bs[128 * 64];
  const int id = blockIdx.x;
  const int sw = (id & 7) * 441 + (id >> 3);   // 3528 = 8 * 441 (bijective)
  const int cti = sw % 18, rti = sw / 18;
  const int ct = cti * 128, rt = rti * 128;
  const int tid = threadIdx.x;
  const int w = tid >> 6, lane = tid & 63;
  const int lr = lane & 15, lg = lane >> 4;
  const int wr = w >> 1, wc = w & 1;

  f32x4 acc[4][4];
  gemm128_core(A, Bt, rt, ct, As, Bs, acc);

  const int s = cti / 6;  // block-uniform: q / k / v
#pragma unroll
  for (int ri = 0; ri < 4; ++ri) {
    const int row = rt + wr * 64 + ri * 16 + lr;
    const int b_ = row / NTOK, n = row % NTOK;
    const int t = n / HW, hw = n % HW;
#pragma unroll
    for (int cj = 0; cj < 4; ++cj) {
      const int colb = ct + wc * 64 + cj * 16 + lg * 4;
      const int rem = colb - s * C;
      const int head = rem / HD, chb = rem - head * HD;
      const int bh = b_ * NH + head;
      if (s == 0) {
        uint2 pk;
        pk.x = pk2(acc[cj][ri][0], acc[cj][ri][1]);
        pk.y = pk2(acc[cj][ri][2], acc[cj][ri][3]);
        *(uint2*)(Qo + (size_t)(bh * T + t) * CHW + hw * HD + chb) = pk;
      } else if (s == 1) {
        uint2 pk;
        pk.x = pk2(acc[cj][ri][0], acc[cj][ri][1]);
        pk.y = pk2(acc[cj][ri][2], acc[cj][ri][3]);
        if (t >= 1)
          *(uint2*)(Ko + (size_t)(bh * T + t - 1) * CHW + hw * HD + chb) = pk;
        if (t == T - 1)
          *(uint2*)(Ko + (size_t)(bh * T + t) * CHW + hw * HD + chb) = pk;
      } else {
#pragma unroll
        for (int j = 0; j < 4; ++j)
          Vo[(size_t)(bh * T + t) * CHW + (chb + j) * HW + hw] = f2b(acc[cj][ri][j]);
      }
    }
  }
}

// ---------------------------------------------------------------------------
// K4: proj GEMM + bias -> out f32.
// ---------------------------------------------------------------------------
__global__ __launch_bounds__(256) void gemm_proj_mfma(
    const bf16* __restrict__ A, const bf16* __restrict__ Bt,
    const float* __restrict__ bias, float* __restrict__ out) {
  __shared__ __align__(16) bf16 As[128 * 64];
  __shared__ __align__(16) bf16 Bs[128 * 64];
  const int id = blockIdx.x;
  const int sw = (id & 7) * 147 + (id >> 3);   // 1176 = 8 * 147 (bijective)
  const int cti = sw % 6, rti = sw / 6;
  const int ct = cti * 128, rt = rti * 128;
  const int tid = threadIdx.x;
  const int w = tid >> 6, lane = tid & 63;
  const int lr = lane & 15, lg = lane >> 4;
  const int wr = w >> 1, wc = w & 1;

  f32x4 acc[4][4];
  gemm128_core(A, Bt, rt, ct, As, Bs, acc);

#pragma unroll
  for (int ri = 0; ri < 4; ++ri) {
    const int row = rt + wr * 64 + ri * 16 + lr;
#pragma unroll
    for (int cj = 0; cj < 4; ++cj) {
      const int colb = ct + wc * 64 + cj * 16 + lg * 4;
      const float4 bv = *(const float4*)(bias + colb);
      float4 o;
      o.x = acc[cj][ri][0] + bv.x;
      o.y = acc[cj][ri][1] + bv.y;
      o.z = acc[cj][ri][2] + bv.z;
      o.w = acc[cj][ri][3] + bv.w;
      *(float4*)(out + (size_t)row * C + colb) = o;
    }
  }
}

// ---------------------------------------------------------------------------
// K2: in-place l2norm over channel dim, X[bt][tok][c] rows. One wave per row.
// ---------------------------------------------------------------------------
__global__ __launch_bounds__(256) void l2norm_rows(bf16* __restrict__ X) {
  const int bt = blockIdx.x;
  const int w = threadIdx.x >> 6, lane = threadIdx.x & 63;
  bf16* base = X + (size_t)bt * CHW;
  for (int r = w; r < HW; r += 4) {
    float v0 = 0.f, v1 = 0.f;
    if (lane < 48) {
      const uint pk = *(const uint*)(base + r * HD + lane * 2);
      v0 = b2f(u2b((ushort)(pk & 0xffff)));
      v1 = b2f(u2b((ushort)(pk >> 16)));
    }
    float s = v0 * v0 + v1 * v1;
#pragma unroll
    for (int off = 32; off; off >>= 1) s += __shfl_xor(s, off);
    const float inv = 1.f / fmaxf(sqrtf(s), 1e-12f);
    if (lane < 48) {
      const uint o = ((uint)b2u(f2b(v0 * inv))) | (((uint)b2u(f2b(v1 * inv))) << 16);
      *(uint*)(base + r * HD + lane * 2) = o;
    }
  }
}

// ---------------------------------------------------------------------------
// K3: fused corr + appearance + motion attention per bt. 512 threads, 8 waves.
// P1: S(MFMA, K from global/L2) -> corr extract -> app softmax -> app PV ->
//     merged = 0.5*app.   barrier.
// P2: M = corrT.corrT^T -> softmax -> PV -> merged += 0.5*motion.
// ---------------------------------------------------------------------------
__global__ __launch_bounds__(512, 2) void fused_attn(
    const bf16* __restrict__ Qg, const bf16* __restrict__ Kg,
    const bf16* __restrict__ Vg, const float* __restrict__ pos,
    bf16* __restrict__ merged) {
  __shared__ __align__(16) bf16 Vt[96 * VW];       // 44,544 B  V^T: ch x tok
  __shared__ __align__(16) bf16 corrT[208 * UW];   // 29,952 B  tok x disp(64pad)
  __shared__ __align__(16) bf16 P[8][16 * VW];     // 59,392 B  per-wave P band
  const int bt = blockIdx.x;
  const int tid = threadIdx.x;
  const int w = tid >> 6, lane = tid & 63;
  const int lr = lane & 15, lg = lane >> 4;

  // ---- P0: staging ----
  {
    const uint* vg = (const uint*)(Vg + (size_t)bt * CHW);    // 96 x 98 u32
    uint* vl = (uint*)Vt;                                     // row = 116 u32
    for (int i = tid; i < 96 * 98; i += 512) { const int c = i / 98, g = i - c * 98; vl[c * 116 + g] = vg[i]; }
    for (int i = tid; i < 96 * 18; i += 512) { const int c = i / 18, g = 98 + i % 18; vl[c * 116 + g] = 0u; }
    uint* ct32 = (uint*)corrT;                                // row = 36 u32
    for (int i = tid; i < 208 * 36; i += 512) {
      const int n = i % 208, up = i / 208;
      const int u0 = 2 * up, u1 = u0 + 1;
      const float p0 = (n < 196 && u0 < 49) ? pos[u0 * 196 + n] : 0.f;
      const float p1 = (n < 196 && u1 < 49) ? pos[u1 * 196 + n] : 0.f;
      ct32[n * 36 + up] = ((uint)b2u(f2b(p0))) | (((uint)b2u(f2b(p1))) << 16);
    }
    uint* p32 = (uint*)P;
    for (int i = tid; i < 8 * 16 * 18; i += 512) { const int row = i / 18, g = 98 + i % 18; p32[row * 116 + g] = 0u; }
  }
  __syncthreads();

  const size_t qbase = (size_t)bt * CHW;
  const int b_ = bt >> 6, head = (bt >> 3) & 7, tt = bt & 7;
  bf16* P_w = P[w];

  // per-lane K row pointers (clamped), static-indexed -> registers
  const bf16* krow[NT];
#pragma unroll
  for (int mt = 0; mt < NT; ++mt) {
    int tok = mt * 16 + lr; if (tok > 195) tok = 195;
    krow[mt] = Kg + qbase + (size_t)tok * HD + lg * 8;
  }

  // ---- P1: S -> corr extract -> app softmax -> app PV -> merged (=) ----
  for (int rt = w; rt < NT; rt += 8) {
    const int rq = (rt * 16 + lr > 195) ? 195 : rt * 16 + lr;
    short8v qa[3];
#pragma unroll
    for (int kc = 0; kc < 3; ++kc)
      qa[kc] = *(const short8v*)(Qg + qbase + (size_t)rq * HD + kc * 32 + lg * 8);
    f32x4 sacc[NT];
#pragma unroll
    for (int mt = 0; mt < NT; ++mt) sacc[mt] = (f32x4){0.f, 0.f, 0.f, 0.f};
#pragma unroll
    for (int kc = 0; kc < 3; ++kc)
#pragma unroll
      for (int mt = 0; mt < NT; ++mt) {
        const short8v bf = *(const short8v*)(krow[mt] + kc * 32);
        sacc[mt] = __builtin_amdgcn_mfma_f32_16x16x32_bf16(qa[kc], bf, sacc[mt], 0, 0, 0);
      }
    // corr extraction into corrT (one writer per (row,u))
#pragma unroll
    for (int j = 0; j < 4; ++j) {
      const int rowg = rt * 16 + lg * 4 + j;
      if (rowg < 196) {
        const int h = rowg / WSP, wq = rowg - (rowg / WSP) * WSP;
#pragma unroll
        for (int mt = 0; mt < NT; ++mt) {
          const int colg = mt * 16 + lr;
          if (colg < 196) {
            const int h2 = colg / WSP, w2 = colg - (colg / WSP) * WSP;
            const int dh = h2 - h + 3, dw = w2 - wq + 3;
            if (((unsigned)dh < 7u) && ((unsigned)dw < 7u)) {
              bf16* cp = &corrT[rowg * UW + dh * 7 + dw];
              *cp = f2b(b2f(*cp) + sacc[mt][j]);
            }
          }
        }
      }
    }
    // app softmax (x0.5) -> P band
#pragma unroll
    for (int j = 0; j < 4; ++j) {
      float mx = -1e30f;
#pragma unroll
      for (int mt = 0; mt < NT; ++mt) {
        float v = sacc[mt][j];
        if (mt == 12 && lr >= 4) v = -1e30f;
        mx = fmaxf(mx, v);
      }
      mx = fmaxf(mx, __shfl_xor(mx, 1)); mx = fmaxf(mx, __shfl_xor(mx, 2));
      mx = fmaxf(mx, __shfl_xor(mx, 4)); mx = fmaxf(mx, __shfl_xor(mx, 8));
      float e[NT], s = 0.f;
#pragma unroll
      for (int mt = 0; mt < NT; ++mt) {
        const float ee = (mt == 12 && lr >= 4) ? 0.f : __expf(sacc[mt][j] - mx);
        e[mt] = ee; s += ee;
      }
      s += __shfl_xor(s, 1); s += __shfl_xor(s, 2); s += __shfl_xor(s, 4); s += __shfl_xor(s, 8);
      const float sc = 0.5f / s;
      const int prow = lg * 4 + j;
#pragma unroll
      for (int mt = 0; mt < NT; ++mt)
        if (mt < 12 || lr < 4) P_w[prow * VW + mt * 16 + lr] = f2b(e[mt] * sc);
    }
    // app PV
    f32x4 pacc[6];
#pragma unroll
    for (int ct = 0; ct < 6; ++ct) pacc[ct] = (f32x4){0.f, 0.f, 0.f, 0.f};
    short8v pf[7];
#pragma unroll
    for (int kp = 0; kp < 7; ++kp) pf[kp] = *(const short8v*)&P_w[lr * VW + kp * 32 + lg * 8];
#pragma unroll
    for (int ct = 0; ct < 6; ++ct)
#pragma unroll
      for (int kp = 0; kp < 7; ++kp) {
        const short8v vf = *(const short8v*)&Vt[(ct * 16 + lr) * VW + kp * 32 + lg * 8];
        pacc[ct] = __builtin_amdgcn_mfma_f32_16x16x32_bf16(pf[kp], vf, pacc[ct], 0, 0, 0);
      }
    // merged = 0.5*app
#pragma unroll
    for (int j = 0; j < 4; ++j) {
      const int rowg = rt * 16 + lg * 4 + j;
      if (rowg < 196) {
        const size_t base = ((size_t)(b_ * NTOK + tt * HW + rowg)) * C + head * HD;
#pragma unroll
        for (int ct = 0; ct < 6; ++ct)
          merged[base + ct * 16 + lr] = f2b(pacc[ct][j]);
      }
    }
  }
  __syncthreads();

  // ---- P2: motion M + softmax + PV -> merged (+=) ----
  for (int rt = w; rt < NT; rt += 8) {
    f32x4 macc[NT];
#pragma unroll
    for (int mt = 0; mt < NT; ++mt) macc[mt] = (f32x4){0.f, 0.f, 0.f, 0.f};
    short8v ca[2];
#pragma unroll
    for (int kc = 0; kc < 2; ++kc)
      ca[kc] = *(const short8v*)&corrT[(rt * 16 + lr) * UW + kc * 32 + lg * 8];
#pragma unroll
    for (int kc = 0; kc < 2; ++kc)
#pragma unroll
      for (int mt = 0; mt < NT; ++mt) {
        const short8v cb = *(const short8v*)&corrT[(mt * 16 + lr) * UW + kc * 32 + lg * 8];
        macc[mt] = __builtin_amdgcn_mfma_f32_16x16x32_bf16(ca[kc], cb, macc[mt], 0, 0, 0);
      }
#pragma unroll
    for (int j = 0; j < 4; ++j) {
      float mx = -1e30f;
#pragma unroll
      for (int mt = 0; mt < NT; ++mt) {
        float v = macc[mt][j];
        if (mt == 12 && lr >= 4) v = -1e30f;
        mx = fmaxf(mx, v);
      }
      mx = fmaxf(mx, __shfl_xor(mx, 1)); mx = fmaxf(mx, __shfl_xor(mx, 2));
      mx = fmaxf(mx, __shfl_xor(mx, 4)); mx = fmaxf(mx, __shfl_xor(mx, 8));
      float e[NT], s = 0.f;
#pragma unroll
      for (int mt = 0; mt < NT; ++mt) {
        const float ee = (mt == 12 && lr >= 4) ? 0.f : __expf(macc[mt][j] - mx);
        e[mt] = ee; s += ee;
      }
      s += __shfl_xor(s, 1); s += __shfl_xor(s, 2); s += __shfl_xor(s, 4); s += __shfl_xor(s, 8);
      const float sc = 0.5f / s;
      const int prow = lg * 4 + j;
#pragma unroll
      for (int mt = 0; mt < NT; ++mt)
        if (mt < 12 || lr < 4) P_w[prow * VW + mt * 16 + lr] = f2b(e[mt] * sc);
    }
    f32x4 pacc[6];
#pragma unroll
    for (int ct = 0; ct < 6; ++ct) pacc[ct] = (f32x4){0.f, 0.f, 0.f, 0.f};
    short8v pf[7];
#pragma unroll
    for (int kp = 0; kp < 7; ++kp) pf[kp] = *(const short8v*)&P_w[lr * VW + kp * 32 + lg * 8];
#pragma unroll
    for (int ct = 0; ct < 6; ++ct)
#pragma unroll
      for (int kp = 0; kp < 7; ++kp) {
        const short8v vf = *(const short8v*)&Vt[(ct * 16 + lr) * VW + kp * 32 + lg * 8];
        pacc[ct] = __builtin_amdgcn_mfma_f32_16x16x32_bf16(pf[kp], vf, pacc[ct], 0, 0, 0);
      }
    // merged += 0.5*motion (same-thread RAW with P1 store)
#pragma unroll
    for (int j = 0; j < 4; ++j) {
      const int rowg = rt * 16 + lg * 4 + j;
      if (rowg < 196) {
        const size_t base = ((size_t)(b_ * NTOK + tt * HW + rowg)) * C + head * HD;
#pragma unroll
        for (int ct = 0; ct < 6; ++ct) {
          const size_t o = base + ct * 16 + lr;
          merged[o] = f2b(b2f(merged[o]) + pacc[ct][j]);
        }
      }
    }
  }
}

}  // namespace

extern "C" void kernel_launch(void* const* d_in, const int* in_sizes, int n_in,
                              void* d_out, int out_size, void* d_ws, size_t ws_size,
                              hipStream_t stream) {
  (void)in_sizes; (void)n_in; (void)out_size; (void)ws_size;
  const float* x      = (const float*)d_in[0];
  const float* w_qkv  = (const float*)d_in[1];
  const float* w_proj = (const float*)d_in[2];
  const float* b_proj = (const float*)d_in[3];
  const float* pos    = (const float*)d_in[4];
  float* out = (float*)d_out;

  char* p = (char*)d_ws;
  bf16* Qb = (bf16*)p;      p += (size_t)BHT * CHW * sizeof(bf16);    // 38.5 MB
  bf16* Kb = (bf16*)p;      p += (size_t)BHT * CHW * sizeof(bf16);    // 38.5 MB
  bf16* Vb = (bf16*)p;      p += (size_t)BHT * CHW * sizeof(bf16);    // 38.5 MB
  bf16* xbm = (bf16*)p;     p += (size_t)NROWS * C * sizeof(bf16);    // 38.5 MB (xb, then merged)
  bf16* wqkvT = (bf16*)p;   p += (size_t)C3 * C * sizeof(bf16);       // 3.5 MB
  bf16* wprojT = (bf16*)p;  p += (size_t)C * C * sizeof(bf16);        // 1.2 MB
  // total ws: ~159 MB

  conv_to_bf16<<<(NROWS * C / 8 + 255) / 256, 256, 0, stream>>>(x, xbm, NROWS * C / 8);
  transpose_to_bf16<<<dim3(C3 / 64, C / 64), 256, 0, stream>>>(w_qkv, wqkvT, C, C3);
  transpose_to_bf16<<<dim3(C / 64, C / 64), 256, 0, stream>>>(w_proj, wprojT, C, C);
  gemm_qkv_mfma<<<3528, 256, 0, stream>>>(xbm, wqkvT, Qb, Kb, Vb);
  l2norm_rows<<<BHT, 256, 0, stream>>>(Qb);
  l2norm_rows<<<BHT, 256, 0, stream>>>(Kb);
  fused_attn<<<BHT, 512, 0, stream>>>(Qb, Kb, Vb, pos, xbm /*merged*/);
  gemm_proj_mfma<<<1176, 256, 0, stream>>>(xbm, wprojT, b_proj, out);
}